// Round 15
// baseline (402.252 us; speedup 1.0000x reference)
//
#include <hip/hip_runtime.h>
#include <hip/hip_bf16.h>

typedef float f4 __attribute__((ext_vector_type(4)));
typedef int i32x4 __attribute__((ext_vector_type(4)));
typedef int i32x8 __attribute__((ext_vector_type(8)));
typedef unsigned short u16x8 __attribute__((ext_vector_type(8)));

#define N_TOK 2048
#define BATCH 8
#define DIM   1024

#if defined(__has_builtin)
#if __has_builtin(__builtin_amdgcn_cvt_scalef32_pk_fp4_f32)
#define HAS_FP4_CVT 1
#endif
#endif

// f32 -> bf16 rne
static __device__ __forceinline__ unsigned short f2bf(float f) {
  unsigned int b = __float_as_uint(f);
  b += 0x7FFFu + ((b >> 16) & 1u);
  return (unsigned short)(b >> 16);
}
static __device__ __forceinline__ float bf2f(unsigned short u) {
  return __uint_as_float(((unsigned int)u) << 16);
}
// fp4 e2m1 encode fallback ladder.  Codes: 0,.5,1,1.5,2,3,4,6 (+sign bit 3).
static __device__ __forceinline__ unsigned int fp4_enc(float v) {
  const float a = fabsf(v);
  unsigned int c = (a >= 0.25f) + (a >= 0.75f) + (a >= 1.25f) + (a >= 1.75f)
                 + (a >= 2.5f) + (a >= 3.5f) + (a >= 5.0f);
  return c | (v < 0.0f ? 8u : 0u);
}
// fp4 e2m1 decode (branchless-ish)
static __device__ __forceinline__ float fp4_dec(unsigned int c) {
  const unsigned int m = c & 7;
  const float mag = (m < 2) ? 0.5f * (float)m
                            : (1.0f + 0.5f * (float)(m & 1)) * (float)(1 << (((m >> 1) & 3) - 1));
  return (c & 8) ? -mag : mag;
}
// pack 8 f32 -> 8 fp4 nibbles (low nibble = v[0]); HW cvt when available
static __device__ __forceinline__ unsigned int pk8_fp4(const float* v) {
#ifdef HAS_FP4_CVT
  unsigned int r = 0;
  r = __builtin_amdgcn_cvt_scalef32_pk_fp4_f32(r, v[0], v[1], 1.0f, 0);
  r = __builtin_amdgcn_cvt_scalef32_pk_fp4_f32(r, v[2], v[3], 1.0f, 1);
  r = __builtin_amdgcn_cvt_scalef32_pk_fp4_f32(r, v[4], v[5], 1.0f, 2);
  r = __builtin_amdgcn_cvt_scalef32_pk_fp4_f32(r, v[6], v[7], 1.0f, 3);
  return r;
#else
  unsigned int r = 0;
  #pragma unroll
  for (int i = 0; i < 8; ++i) r |= fp4_enc(v[i]) << (i * 4);
  return r;
#endif
}
// pack 2 f32 -> one fp4 byte (low nibble = a)
static __device__ __forceinline__ unsigned int pk2_fp4(float a, float b) {
#ifdef HAS_FP4_CVT
  return __builtin_amdgcn_cvt_scalef32_pk_fp4_f32(0u, a, b, 1.0f, 0) & 0xFFu;
#else
  return fp4_enc(a) | (fp4_enc(b) << 4);
#endif
}

static __device__ __forceinline__ void gld16(const void* g, void* lds) {
  __builtin_amdgcn_global_load_lds(
      (const __attribute__((address_space(1))) unsigned int*)g,
      (__attribute__((address_space(3))) unsigned int*)lds, 16, 0, 0);
}

// Stage a [128 rows x 128 byte] tile into 16 KB LDS with 256 threads
// (4 x gld16 each).  Linear LDS dest, XOR-swizzled per-lane global source
// (G21): LDS[row*128 + (g16 ^ ((row&7)<<4))] = G[row][g16] per 16B granule.
static __device__ __forceinline__ void stage_tile(const unsigned char* g, size_t ldb,
                                                  unsigned char* lds, int w, int l) {
  const int rgrp = l >> 3;                       // row within 8-row granule
  const int srcb = (((l & 7) ^ rgrp) << 4);      // swizzled byte offset in row
  #pragma unroll
  for (int gi = 0; gi < 4; ++gi) {
    int rb = (gi * 4 + w) * 8;                   // wave-granule base row
    gld16(g + (size_t)(rb + rgrp) * ldb + srcb, lds + (gi * 4 + w) * 1024);
  }
}

// 16B fp4 fragment (K=128 at 4 bit): one granule, data in regs 0-3.
static __device__ __forceinline__ i32x8 fragld16(const unsigned char* lds, int row, int kb) {
  const i32x4 lo = *(const i32x4*)(lds + row * 128 + (kb ^ ((row & 7) << 4)));
  i32x8 r;
  r[0] = lo[0]; r[1] = lo[1]; r[2] = lo[2]; r[3] = lo[3];
  r[4] = 0; r[5] = 0; r[6] = 0; r[7] = 0;
  return r;
}

// fp4 x fp4 MX K-loop (R13-proven single-buffer): BK=256, TWO 16KB tiles
// staged, 2 substeps of 16 mfma_scale K=128.  cbsz=blgp=4, scale 0x7F = 1.0.
static __device__ __forceinline__ void gemm_fp4(unsigned char* sA, unsigned char* sB,
    const unsigned char* Ab, size_t lda, const unsigned char* Bb, size_t ldb,
    int nko, int w, int l, int wr, int wc, f4 acc[4][4]) {
  for (int kk = 0; kk < nko; ++kk) {
    stage_tile(Ab + (size_t)kk * 128, lda, sA, w, l);
    stage_tile(Bb + (size_t)kk * 128, ldb, sB, w, l);
    __syncthreads();
    #pragma unroll
    for (int ks = 0; ks < 2; ++ks) {
      const int kb = ks * 64 + (l >> 4) * 16;
      i32x8 af[4], bf[4];
      #pragma unroll
      for (int i = 0; i < 4; ++i)
        af[i] = fragld16(sA, wr * 64 + i * 16 + (l & 15), kb);
      #pragma unroll
      for (int j = 0; j < 4; ++j)
        bf[j] = fragld16(sB, wc * 64 + j * 16 + (l & 15), kb);
      #pragma unroll
      for (int i = 0; i < 4; ++i)
        #pragma unroll
        for (int j = 0; j < 4; ++j)
          acc[i][j] = __builtin_amdgcn_mfma_scale_f32_16x16x128_f8f6f4(
              af[i], bf[j], acc[i][j], 4, 4, 0, 0x7F7F7F7F, 0, 0x7F7F7F7F);
    }
    __syncthreads();
  }
}

// ---------------- prep kernels ----------------

static __device__ __forceinline__ float block_reduce_sum(float v, volatile float* sb, int t) {
  #pragma unroll
  for (int o = 32; o; o >>= 1) v += __shfl_xor(v, o);
  if ((t & 63) == 0) sb[t >> 6] = v;
  __syncthreads();
  float r = sb[0] + sb[1] + sb[2] + sb[3];
  __syncthreads();
  return r;
}

// embed -> RAW fp4 wn4 (adjacent-d nibble pairs, matching xr4) + winv[n]
__global__ __launch_bounds__(256) void prep_wn(const float* __restrict__ e,
                                               unsigned char* __restrict__ wn4,
                                               float* __restrict__ winv) {
  __shared__ float sb[4];
  const int n = blockIdx.x, t = threadIdx.x;
  const float4 v = *(const float4*)(e + (size_t)n * DIM + t * 4);
  float ss = v.x * v.x + v.y * v.y + v.z * v.z + v.w * v.w;
  ss = block_reduce_sum(ss, sb, t);
  if (t == 0) winv[n] = rsqrtf(fmaxf(ss, 1e-24f));
  float f[8];
  f[0] = v.x; f[1] = v.y; f[2] = v.z; f[3] = v.w;
  f[4] = 0.0f; f[5] = 0.0f; f[6] = 0.0f; f[7] = 0.0f;
  *(unsigned short*)(wn4 + ((size_t)n * DIM + t * 4) / 2) =
      (unsigned short)(pk8_fp4(f) & 0xFFFFu);
}

// Fused x pass (reads x ONCE): raw fp4 in BOTH layouts (d-packed xr4 [b][m][d/2],
// m-packed XT4 [b][d][m/2]; low nibble = even k) + optional bf16 copy + ss
// partials + per-64m colsum partials of x-hat (csp[b][d][32]).
template <int XBF>
__global__ __launch_bounds__(256) void prep_x(const float* __restrict__ x,
    unsigned char* __restrict__ xr4, unsigned char* __restrict__ XT4,
    unsigned short* __restrict__ xbf, float* __restrict__ sspart,
    float* __restrict__ csp) {
  __shared__ unsigned char tile[64][36];   // packed fp4 pairs along d
  const int t = threadIdx.x;
  const int m0 = blockIdx.x * 64, d0 = blockIdx.y * 64, b = blockIdx.z;
  {
    const int ml = t >> 2, dc = (t & 3) * 16;
    const size_t roff = ((size_t)(m0 + ml) * BATCH + b) * DIM + d0 + dc;
    const float* row = x + roff;
    float f[16];
    union { unsigned short u[16]; u16x8 v[2]; } bfp;
    float ssp = 0.0f;
    #pragma unroll
    for (int i = 0; i < 4; ++i) {
      float4 v = *(const float4*)(row + i * 4);
      ssp += v.x * v.x + v.y * v.y + v.z * v.z + v.w * v.w;
      f[i * 4 + 0] = v.x; f[i * 4 + 1] = v.y;
      f[i * 4 + 2] = v.z; f[i * 4 + 3] = v.w;
      if (XBF) {
        bfp.u[i * 4 + 0] = f2bf(v.x); bfp.u[i * 4 + 1] = f2bf(v.y);
        bfp.u[i * 4 + 2] = f2bf(v.z); bfp.u[i * 4 + 3] = f2bf(v.w);
      }
    }
    union { unsigned int u[2]; uint2 v; } pk;
    pk.u[0] = pk8_fp4(f);
    pk.u[1] = pk8_fp4(f + 8);
    *(uint2*)(xr4 + (((size_t)b * N_TOK + m0 + ml) * DIM + d0 + dc) / 2) = pk.v;
    *(unsigned int*)&tile[ml][(t & 3) * 8] = pk.u[0];
    *(unsigned int*)&tile[ml][(t & 3) * 8 + 4] = pk.u[1];
    if (XBF) {
      *(u16x8*)(xbf + roff) = bfp.v[0];
      *(u16x8*)(xbf + roff + 8) = bfp.v[1];
    }
    ssp += __shfl_xor(ssp, 1);
    ssp += __shfl_xor(ssp, 2);
    if ((t & 3) == 0)
      sspart[((size_t)b * N_TOK + m0 + ml) * 16 + (d0 >> 6)] = ssp;
  }
  __syncthreads();
  {
    const int dl = t >> 2, mc = (t & 3) * 16;
    const int sh = (dl & 1) * 4, dby = dl >> 1;
    union { unsigned int u[2]; uint2 v; } o;
    o.u[0] = o.u[1] = 0;
    float cs = 0.0f;
    #pragma unroll
    for (int jj = 0; jj < 8; ++jj) {
      const unsigned int b0 = ((unsigned int)tile[mc + 2 * jj][dby] >> sh) & 15u;
      const unsigned int b1 = ((unsigned int)tile[mc + 2 * jj + 1][dby] >> sh) & 15u;
      o.u[jj >> 2] |= (b0 | (b1 << 4)) << ((jj & 3) * 8);
      cs += fp4_dec(b0) + fp4_dec(b1);
    }
    *(uint2*)(XT4 + (((size_t)b * DIM + d0 + dl) * (size_t)N_TOK + m0 + mc) / 2) = o.v;
    // colsum of x-hat over this block's 64 m (4 threads share one d)
    cs += __shfl_xor(cs, 1);
    cs += __shfl_xor(cs, 2);
    if ((t & 3) == 0)
      csp[((size_t)b * DIM + d0 + dl) * 32 + (m0 >> 6)] = cs;
  }
}

// ---------------- GEMM A: Sraw = wn4(fp4).xr4(fp4)^T ; delta' = 32*(exp(S)-1) fp4 ----------------

__global__ __launch_bounds__(256, 4) void kA(
    const unsigned char* __restrict__ wn4, const unsigned char* __restrict__ xr4,
    const float* __restrict__ winv, const float* __restrict__ sspart,
    unsigned char* __restrict__ Pd4, float* __restrict__ pden, int Mc, int c0) {
  __shared__ __align__(16) unsigned char sA[16384];
  __shared__ __align__(16) unsigned char sB[16384];
  __shared__ float pd[128][2];
  __shared__ float winv_s[128], xinv_s[128];

  const int t = threadIdx.x, l = t & 63, w = t >> 6;
  const int wr = w >> 1, wc = w & 1;

  // T1: chunked XCD swizzle (grid (16, Mc/128, 8); nwg % 8 == 0 -> bijective).
  const int gy = Mc >> 7;
  const int nwg = 16 * gy * 8;
  const int lin = blockIdx.x + 16 * (blockIdx.y + gy * blockIdx.z);
  const int wg = (lin & 7) * (nwg >> 3) + (lin >> 3);
  const int xx = wg & 15, yy = (wg >> 4) % gy, zz = (wg >> 4) / gy;

  const int q0 = xx * 128;
  const int m0l = yy * 128;
  const int b = zz;
  const int m0g = c0 + m0l;

  if (t < 128) {
    winv_s[t] = winv[q0 + t];
  } else {
    const float* p = sspart + ((size_t)b * N_TOK + m0g + (t - 128)) * 16;
    float s = 0.0f;
    #pragma unroll
    for (int k = 0; k < 16; ++k) s += p[k];
    xinv_s[t - 128] = rsqrtf(fmaxf(s, 1e-24f));
  }

  f4 acc[4][4];
  #pragma unroll
  for (int i = 0; i < 4; ++i)
    #pragma unroll
    for (int j = 0; j < 4; ++j) acc[i][j] = (f4)0.0f;

  gemm_fp4(sA, sB,
           wn4 + (size_t)q0 * (DIM / 2), DIM / 2,
           xr4 + ((size_t)b * N_TOK + m0g) * (DIM / 2), DIM / 2,
           DIM / 256, w, l, wr, wc, acc);

  // epilogue: S in [-1,1]; p = exp(S); store delta' = 32*(p-1) as fp4 nibble
  // pairs (even lane packs own + odd-neighbor value); exact-f32 row sums.
  float ra[4][4];
  #pragma unroll
  for (int i = 0; i < 4; ++i)
    #pragma unroll
    for (int e = 0; e < 4; ++e) ra[i][e] = 0.0f;

  #pragma unroll
  for (int j = 0; j < 4; ++j) {
    const int cl = wc * 64 + j * 16 + (l & 15);  // local m col
    const float xv = xinv_s[cl];
    #pragma unroll
    for (int i = 0; i < 4; ++i)
      #pragma unroll
      for (int e = 0; e < 4; ++e) {
        const int row = wr * 64 + i * 16 + (l >> 4) * 4 + e;  // local q
        const float p = __expf(acc[i][j][e] * winv_s[row] * xv);
        ra[i][e] += p;
        const float dv = 32.0f * (p - 1.0f);
        const float pdv = __shfl_xor(dv, 1);
        if (!(l & 1)) {
          Pd4[(((size_t)b * N_TOK + q0 + row) * (size_t)Mc + m0l + cl) >> 1] =
              (unsigned char)pk2_fp4(dv, pdv);
        }
      }
  }
  #pragma unroll
  for (int i = 0; i < 4; ++i)
    #pragma unroll
    for (int e = 0; e < 4; ++e) {
      float s = ra[i][e];
      s += __shfl_xor(s, 1); s += __shfl_xor(s, 2);
      s += __shfl_xor(s, 4); s += __shfl_xor(s, 8);
      if ((l & 15) == 0) pd[wr * 64 + i * 16 + (l >> 4) * 4 + e][wc] = s;
    }
  __syncthreads();
  if (t < 128)
    pden[((size_t)b * N_TOK + q0 + t) * 16 + (c0 >> 7) + yy] = pd[t][0] + pd[t][1];
}

// ---------------- GEMM B: acc = delta'(fp4) . XT4(fp4)^T ;
// O = (colsum(x-hat) + acc/32) * rden ; FINAL writes bf16 if OBF ----------------

template <int ACC, int FINAL, int OBF>
__global__ __launch_bounds__(256, 4) void kB(const unsigned char* __restrict__ Pd4,
    const unsigned char* __restrict__ XT4, const float* __restrict__ pden,
    const float* __restrict__ csp, float* __restrict__ of32,
    unsigned short* __restrict__ obf, int Mc, int c0) {
  __shared__ __align__(16) unsigned char sA[16384];
  __shared__ __align__(16) unsigned char sB[16384];
  __shared__ float rden_s[128];
  __shared__ float csum_s[128];

  const int t = threadIdx.x, l = t & 63, w = t >> 6;
  const int wr = w >> 1, wc = w & 1;

  // T1: chunked XCD swizzle, d0-INNER within XCD (delta q-panel co-resident).
  const int lin = blockIdx.x + 16 * (blockIdx.y + 8 * blockIdx.z);
  const int wg = (lin & 7) * 128 + (lin >> 3);
  const int s = wg & 127;
  const int d0 = (s & 7) * 128;
  const int q0 = (s >> 3) * 128;
  const int b = wg >> 7;

  f4 acc[4][4];
  #pragma unroll
  for (int i = 0; i < 4; ++i)
    #pragma unroll
    for (int j = 0; j < 4; ++j) acc[i][j] = (f4)0.0f;

  gemm_fp4(sA, sB,
           Pd4 + ((size_t)b * N_TOK + q0) * (size_t)(Mc / 2), (size_t)Mc / 2,
           XT4 + (((size_t)b * DIM + d0) * (size_t)N_TOK + c0) / 2, N_TOK / 2,
           Mc / 256, w, l, wr, wc, acc);

  if (FINAL) {
    if (t < 128) {
      const float* pp = pden + ((size_t)b * N_TOK + q0 + t) * 16;
      float ss = 0.0f;
      #pragma unroll
      for (int i = 0; i < 16; ++i) ss += pp[i];
      rden_s[t] = 1.0f / ss;
    } else {
      const float* cp = csp + ((size_t)b * DIM + d0 + (t - 128)) * 32;
      float cs = 0.0f;
      #pragma unroll
      for (int g = 0; g < 32; ++g) cs += cp[g];
      csum_s[t - 128] = cs;
    }
    __syncthreads();
  }

  #pragma unroll
  for (int j = 0; j < 4; ++j) {
    const int cl = wc * 64 + j * 16 + (l & 15);
    const int cc = d0 + cl;
    #pragma unroll
    for (int i = 0; i < 4; ++i)
      #pragma unroll
      for (int e = 0; e < 4; ++e) {
        const int rl = wr * 64 + i * 16 + (l >> 4) * 4 + e;
        const size_t oi = (size_t)(q0 + rl) * (BATCH * DIM) + (size_t)b * DIM + cc;
        float v = acc[i][j][e] * 0.03125f;     // /32 delta scale
        if (ACC) v += of32[oi];
        if (FINAL) {
          v = (v + csum_s[cl]) * rden_s[rl];
          if (OBF) { obf[oi] = f2bf(v); continue; }
        }
        of32[oi] = v;
      }
  }
}

// ---------------- final: out = LN(O + x) * gamma + beta ----------------

template <int OBF, int XBF>
__global__ __launch_bounds__(256) void kLN(const float* __restrict__ gamma,
    const float* __restrict__ beta, const unsigned short* __restrict__ obf,
    const float* __restrict__ of32, const unsigned short* __restrict__ xbf,
    const float* __restrict__ x, float* __restrict__ out) {
  __shared__ float sb[8];
  const int r = blockIdx.x;            // r = n*8 + b
  const int t = threadIdx.x;

  const size_t base = (size_t)r * DIM + t * 4;
  float o0, o1, o2, o3, x0, x1, x2, x3;
  if (OBF) {
    const ushort4 u = *(const ushort4*)(obf + base);
    o0 = bf2f(u.x); o1 = bf2f(u.y); o2 = bf2f(u.z); o3 = bf2f(u.w);
  } else {
    const float4 o4 = *(const float4*)(of32 + base);
    o0 = o4.x; o1 = o4.y; o2 = o4.z; o3 = o4.w;
  }
  if (XBF) {
    const ushort4 u = *(const ushort4*)(xbf + base);
    x0 = bf2f(u.x); x1 = bf2f(u.y); x2 = bf2f(u.z); x3 = bf2f(u.w);
  } else {
    const float4 x4 = *(const float4*)(x + base);
    x0 = x4.x; x1 = x4.y; x2 = x4.z; x3 = x4.w;
  }
  const float y0 = o0 + x0, y1 = o1 + x1, y2 = o2 + x2, y3 = o3 + x3;

  float s1 = y0 + y1 + y2 + y3;
  float s2 = y0 * y0 + y1 * y1 + y2 * y2 + y3 * y3;
  #pragma unroll
  for (int o = 32; o; o >>= 1) { s1 += __shfl_xor(s1, o); s2 += __shfl_xor(s2, o); }
  if ((t & 63) == 0) { sb[t >> 6] = s1; sb[4 + (t >> 6)] = s2; }
  __syncthreads();
  s1 = sb[0] + sb[1] + sb[2] + sb[3];
  s2 = sb[4] + sb[5] + sb[6] + sb[7];

  const float mean = s1 * (1.0f / DIM);
  const float var = s2 * (1.0f / DIM) - mean * mean;
  const float rstd = rsqrtf(var + 1e-5f);

  const float4 g4 = *(const float4*)(gamma + t * 4);
  const float4 b4 = *(const float4*)(beta + t * 4);
  float4 rr;
  rr.x = (y0 - mean) * rstd * g4.x + b4.x;
  rr.y = (y1 - mean) * rstd * g4.y + b4.y;
  rr.z = (y2 - mean) * rstd * g4.z + b4.z;
  rr.w = (y3 - mean) * rstd * g4.w + b4.w;
  *(float4*)(out + (size_t)r * DIM + t * 4) = rr;
}

// ---------------- launch ----------------

extern "C" void kernel_launch(void* const* d_in, const int* in_sizes, int n_in,
                              void* d_out, int out_size, void* d_ws, size_t ws_size,
                              hipStream_t stream) {
  (void)in_sizes; (void)n_in; (void)out_size;
  const float* x     = (const float*)d_in[0];
  const float* embed = (const float*)d_in[1];
  const float* gamma = (const float*)d_in[2];
  const float* beta  = (const float*)d_in[3];
  float* out = (float*)d_out;

  size_t off = 0;
  char* ws = (char*)d_ws;
  auto take = [&](size_t bytes) { char* p = ws + off; off += bytes; return p; };
  unsigned char* XT4  = (unsigned char*)take((size_t)BATCH * DIM * N_TOK / 2);  //  8.4 MB
  unsigned char* xr4  = (unsigned char*)take((size_t)BATCH * N_TOK * DIM / 2);  //  8.4 MB
  unsigned char* wn4  = (unsigned char*)take((size_t)N_TOK * DIM / 2);          //  1.0 MB
  float* winv   = (float*)take((size_t)N_TOK * 4);                              //  8 KB
  float* sspart = (float*)take((size_t)BATCH * N_TOK * 16 * 4);                 //  2.1 MB
  float* pden   = (float*)take((size_t)BATCH * N_TOK * 16 * 4);                 //  2.1 MB
  float* csp    = (float*)take((size_t)BATCH * DIM * 32 * 4);                   //  1.0 MB
  const size_t fixed = off;

  int Mc = 2048;
  while (Mc > 256 && fixed + (size_t)BATCH * N_TOK * Mc / 2 > ws_size) Mc >>= 1;
  unsigned char* Pd4 = (unsigned char*)take((size_t)BATCH * N_TOK * Mc / 2);    // 16.8 MB full

  const size_t half = (size_t)N_TOK * BATCH * DIM * 2;                          // 33.6 MB
  const int use_obf = (off + half <= ws_size) ? 1 : 0;
  unsigned short* obf = use_obf ? (unsigned short*)take(half) : (unsigned short*)out;
  const int use_xbf = (off + half <= ws_size) ? 1 : 0;
  unsigned short* xbf = use_xbf ? (unsigned short*)take(half) : (unsigned short*)out;

  prep_wn<<<N_TOK, 256, 0, stream>>>(embed, wn4, winv);
  if (use_xbf)
    prep_x<1><<<dim3(N_TOK / 64, DIM / 64, BATCH), 256, 0, stream>>>(x, xr4, XT4, xbf, sspart, csp);
  else
    prep_x<0><<<dim3(N_TOK / 64, DIM / 64, BATCH), 256, 0, stream>>>(x, xr4, XT4, xbf, sspart, csp);

  const int nchunk = N_TOK / Mc;
  for (int ci = 0; ci < nchunk; ++ci) {
    const int c0 = ci * Mc;
    kA<<<dim3(16, Mc / 128, BATCH), 256, 0, stream>>>(wn4, xr4, winv, sspart, Pd4, pden, Mc, c0);
    const bool first = (ci == 0), last = (ci == nchunk - 1);
    const dim3 gB(16, 8, BATCH);
    if (last) {
      if (use_obf) {
        if (first) kB<0, 1, 1><<<gB, 256, 0, stream>>>(Pd4, XT4, pden, csp, out, obf, Mc, c0);
        else       kB<1, 1, 1><<<gB, 256, 0, stream>>>(Pd4, XT4, pden, csp, out, obf, Mc, c0);
      } else {
        if (first) kB<0, 1, 0><<<gB, 256, 0, stream>>>(Pd4, XT4, pden, csp, out, obf, Mc, c0);
        else       kB<1, 1, 0><<<gB, 256, 0, stream>>>(Pd4, XT4, pden, csp, out, obf, Mc, c0);
      }
    } else {
      if (first) kB<0, 0, 0><<<gB, 256, 0, stream>>>(Pd4, XT4, pden, csp, out, obf, Mc, c0);
      else       kB<1, 0, 0><<<gB, 256, 0, stream>>>(Pd4, XT4, pden, csp, out, obf, Mc, c0);
    }
  }
  if (use_obf) {
    if (use_xbf) kLN<1, 1><<<N_TOK * BATCH, 256, 0, stream>>>(gamma, beta, obf, out, xbf, x, out);
    else         kLN<1, 0><<<N_TOK * BATCH, 256, 0, stream>>>(gamma, beta, obf, out, xbf, x, out);
  } else {
    if (use_xbf) kLN<0, 1><<<N_TOK * BATCH, 256, 0, stream>>>(gamma, beta, obf, out, xbf, x, out);
    else         kLN<0, 0><<<N_TOK * BATCH, 256, 0, stream>>>(gamma, beta, obf, out, xbf, x, out);
  }
}

// Round 16
// 125.396 us; speedup vs baseline: 3.2079x; 3.2079x over previous
//
#include <hip/hip_runtime.h>
#include <hip/hip_bf16.h>

typedef float f4 __attribute__((ext_vector_type(4)));
typedef int i32x4 __attribute__((ext_vector_type(4)));
typedef int i32x8 __attribute__((ext_vector_type(8)));
typedef unsigned char u8x16 __attribute__((ext_vector_type(16)));
typedef unsigned short u16x8 __attribute__((ext_vector_type(8)));

#define N_TOK 2048
#define BATCH 8
#define DIM   1024

#if defined(__has_builtin)
#if __has_builtin(__builtin_amdgcn_cvt_scalef32_pk_fp4_f32)
#define HAS_FP4_CVT 1
#endif
#endif

// ---- fp8 e4m3 (OCP) pack helpers ----
static __device__ __forceinline__ unsigned char fp8_1(float a) {
  return (unsigned char)(__builtin_amdgcn_cvt_pk_fp8_f32(a, a, 0, false) & 0xFF);
}
// f32 -> bf16 rne
static __device__ __forceinline__ unsigned short f2bf(float f) {
  unsigned int b = __float_as_uint(f);
  b += 0x7FFFu + ((b >> 16) & 1u);
  return (unsigned short)(b >> 16);
}
static __device__ __forceinline__ float bf2f(unsigned short u) {
  return __uint_as_float(((unsigned int)u) << 16);
}
// fp4 e2m1 encode fallback ladder.  Codes: 0,.5,1,1.5,2,3,4,6 (+sign bit 3).
static __device__ __forceinline__ unsigned int fp4_enc(float v) {
  const float a = fabsf(v);
  unsigned int c = (a >= 0.25f) + (a >= 0.75f) + (a >= 1.25f) + (a >= 1.75f)
                 + (a >= 2.5f) + (a >= 3.5f) + (a >= 5.0f);
  return c | (v < 0.0f ? 8u : 0u);
}
// pack 8 f32 -> 8 fp4 nibbles (low nibble = v[0]); HW cvt when available
static __device__ __forceinline__ unsigned int pk8_fp4(const float* v) {
#ifdef HAS_FP4_CVT
  unsigned int r = 0;
  r = __builtin_amdgcn_cvt_scalef32_pk_fp4_f32(r, v[0], v[1], 1.0f, 0);
  r = __builtin_amdgcn_cvt_scalef32_pk_fp4_f32(r, v[2], v[3], 1.0f, 1);
  r = __builtin_amdgcn_cvt_scalef32_pk_fp4_f32(r, v[4], v[5], 1.0f, 2);
  r = __builtin_amdgcn_cvt_scalef32_pk_fp4_f32(r, v[6], v[7], 1.0f, 3);
  return r;
#else
  unsigned int r = 0;
  #pragma unroll
  for (int i = 0; i < 8; ++i) r |= fp4_enc(v[i]) << (i * 4);
  return r;
#endif
}

static __device__ __forceinline__ void gld16(const void* g, void* lds) {
  __builtin_amdgcn_global_load_lds(
      (const __attribute__((address_space(1))) unsigned int*)g,
      (__attribute__((address_space(3))) unsigned int*)lds, 16, 0, 0);
}

// Stage a [128 rows x 128 byte] tile into 16 KB LDS with 256 threads
// (4 x gld16 each).  Linear LDS dest, XOR-swizzled per-lane global source
// (G21): LDS[row*128 + (g16 ^ ((row&7)<<4))] = G[row][g16] per 16B granule.
static __device__ __forceinline__ void stage_tile(const unsigned char* g, size_t ldb,
                                                  unsigned char* lds, int w, int l) {
  const int rgrp = l >> 3;                       // row within 8-row granule
  const int srcb = (((l & 7) ^ rgrp) << 4);      // swizzled byte offset in row
  #pragma unroll
  for (int gi = 0; gi < 4; ++gi) {
    int rb = (gi * 4 + w) * 8;                   // wave-granule base row
    gld16(g + (size_t)(rb + rgrp) * ldb + srcb, lds + (gi * 4 + w) * 1024);
  }
}

// 32B fp8 fragment (K=128): two 16B granules, swizzle-aware.  kb 32B-aligned.
static __device__ __forceinline__ i32x8 fragld32(const unsigned char* lds, int row, int kb) {
  const unsigned char* base = lds + row * 128;
  const int swz = (row & 7) << 4;
  const i32x4 lo = *(const i32x4*)(base + (kb ^ swz));
  const i32x4 hi = *(const i32x4*)(base + ((kb + 16) ^ swz));
  i32x8 r;
  r[0] = lo[0]; r[1] = lo[1]; r[2] = lo[2]; r[3] = lo[3];
  r[4] = hi[0]; r[5] = hi[1]; r[6] = hi[2]; r[7] = hi[3];
  return r;
}
// 16B fp4 fragment (K=128 at 4 bit): one granule, data in regs 0-3.
static __device__ __forceinline__ i32x8 fragld16(const unsigned char* lds, int row, int kb) {
  const i32x4 lo = *(const i32x4*)(lds + row * 128 + (kb ^ ((row & 7) << 4)));
  i32x8 r;
  r[0] = lo[0]; r[1] = lo[1]; r[2] = lo[2]; r[3] = lo[3];
  r[4] = 0; r[5] = 0; r[6] = 0; r[7] = 0;
  return r;
}

// fp4 x fp4 MX K-loop (kA): BK=256, TWO 16KB tiles staged, 2 substeps of
// 16 mfma_scale K=128.  cbsz=blgp=4 (fp4), scale 0x7F = 1.0 exact.
static __device__ __forceinline__ void gemm_fp4(unsigned char* sA, unsigned char* sB,
    const unsigned char* Ab, size_t lda, const unsigned char* Bb, size_t ldb,
    int nko, int w, int l, int wr, int wc, f4 acc[4][4]) {
  for (int kk = 0; kk < nko; ++kk) {
    stage_tile(Ab + (size_t)kk * 128, lda, sA, w, l);
    stage_tile(Bb + (size_t)kk * 128, ldb, sB, w, l);
    __syncthreads();
    #pragma unroll
    for (int ks = 0; ks < 2; ++ks) {
      const int kb = ks * 64 + (l >> 4) * 16;
      i32x8 af[4], bf[4];
      #pragma unroll
      for (int i = 0; i < 4; ++i)
        af[i] = fragld16(sA, wr * 64 + i * 16 + (l & 15), kb);
      #pragma unroll
      for (int j = 0; j < 4; ++j)
        bf[j] = fragld16(sB, wc * 64 + j * 16 + (l & 15), kb);
      #pragma unroll
      for (int i = 0; i < 4; ++i)
        #pragma unroll
        for (int j = 0; j < 4; ++j)
          acc[i][j] = __builtin_amdgcn_mfma_scale_f32_16x16x128_f8f6f4(
              af[i], bf[j], acc[i][j], 4, 4, 0, 0x7F7F7F7F, 0, 0x7F7F7F7F);
    }
    __syncthreads();
  }
}

// Mixed-format MX K-loop (kB): A fp8 (cbsz=0), B fp4 (blgp=4), BK=256.
static __device__ __forceinline__ void gemm_mixed(unsigned char* sA0, unsigned char* sA1,
    unsigned char* sB, const unsigned char* Ab, size_t lda,
    const unsigned char* Bb, size_t ldb, int nko, int w, int l, int wr, int wc,
    f4 acc[4][4]) {
  for (int kk = 0; kk < nko; ++kk) {
    stage_tile(Ab + (size_t)kk * 256, lda, sA0, w, l);
    stage_tile(Ab + (size_t)kk * 256 + 128, lda, sA1, w, l);
    stage_tile(Bb + (size_t)kk * 128, ldb, sB, w, l);
    __syncthreads();
    #pragma unroll
    for (int ks = 0; ks < 2; ++ks) {
      const unsigned char* sA = ks ? sA1 : sA0;
      const int kbA = (l >> 4) * 32;
      const int kbB = ks * 64 + (l >> 4) * 16;
      i32x8 af[4], bf[4];
      #pragma unroll
      for (int i = 0; i < 4; ++i)
        af[i] = fragld32(sA, wr * 64 + i * 16 + (l & 15), kbA);
      #pragma unroll
      for (int j = 0; j < 4; ++j)
        bf[j] = fragld16(sB, wc * 64 + j * 16 + (l & 15), kbB);
      #pragma unroll
      for (int i = 0; i < 4; ++i)
        #pragma unroll
        for (int j = 0; j < 4; ++j)
          acc[i][j] = __builtin_amdgcn_mfma_scale_f32_16x16x128_f8f6f4(
              af[i], bf[j], acc[i][j], 0, 4, 0, 0x7F7F7F7F, 0, 0x7F7F7F7F);
    }
    __syncthreads();
  }
}

// ---------------- prep kernels ----------------

static __device__ __forceinline__ float block_reduce_sum(float v, volatile float* sb, int t) {
  #pragma unroll
  for (int o = 32; o; o >>= 1) v += __shfl_xor(v, o);
  if ((t & 63) == 0) sb[t >> 6] = v;
  __syncthreads();
  float r = sb[0] + sb[1] + sb[2] + sb[3];
  __syncthreads();
  return r;
}

// embed -> RAW fp4 wn4 (adjacent-d nibble pairs, matching xr4) + winv[n]
__global__ __launch_bounds__(256) void prep_wn(const float* __restrict__ e,
                                               unsigned char* __restrict__ wn4,
                                               float* __restrict__ winv) {
  __shared__ float sb[4];
  const int n = blockIdx.x, t = threadIdx.x;
  const float4 v = *(const float4*)(e + (size_t)n * DIM + t * 4);
  float ss = v.x * v.x + v.y * v.y + v.z * v.z + v.w * v.w;
  ss = block_reduce_sum(ss, sb, t);
  if (t == 0) winv[n] = rsqrtf(fmaxf(ss, 1e-24f));
  float f[8];
  f[0] = v.x; f[1] = v.y; f[2] = v.z; f[3] = v.w;
  f[4] = 0.0f; f[5] = 0.0f; f[6] = 0.0f; f[7] = 0.0f;
  *(unsigned short*)(wn4 + ((size_t)n * DIM + t * 4) / 2) =
      (unsigned short)(pk8_fp4(f) & 0xFFFFu);
}

// Fused x pass (reads x ONCE): raw fp4 in BOTH layouts (d-packed xr4 [b][m][d/2],
// m-packed XT4 [b][d][m/2]; low nibble = even k) + optional bf16 copy + ss partials.
// LDS tile holds PACKED bytes (2 codes/byte), stride 36 (odd dwords -> <=2-way).
template <int XBF>
__global__ __launch_bounds__(256) void prep_x(const float* __restrict__ x,
    unsigned char* __restrict__ xr4, unsigned char* __restrict__ XT4,
    unsigned short* __restrict__ xbf, float* __restrict__ sspart) {
  __shared__ unsigned char tile[64][36];   // packed fp4 pairs along d
  const int t = threadIdx.x;
  const int m0 = blockIdx.x * 64, d0 = blockIdx.y * 64, b = blockIdx.z;
  {
    const int ml = t >> 2, dc = (t & 3) * 16;
    const size_t roff = ((size_t)(m0 + ml) * BATCH + b) * DIM + d0 + dc;
    const float* row = x + roff;
    float f[16];
    union { unsigned short u[16]; u16x8 v[2]; } bfp;
    float ssp = 0.0f;
    #pragma unroll
    for (int i = 0; i < 4; ++i) {
      float4 v = *(const float4*)(row + i * 4);
      ssp += v.x * v.x + v.y * v.y + v.z * v.z + v.w * v.w;
      f[i * 4 + 0] = v.x; f[i * 4 + 1] = v.y;
      f[i * 4 + 2] = v.z; f[i * 4 + 3] = v.w;
      if (XBF) {
        bfp.u[i * 4 + 0] = f2bf(v.x); bfp.u[i * 4 + 1] = f2bf(v.y);
        bfp.u[i * 4 + 2] = f2bf(v.z); bfp.u[i * 4 + 3] = f2bf(v.w);
      }
    }
    union { unsigned int u[2]; uint2 v; } pk;
    pk.u[0] = pk8_fp4(f);
    pk.u[1] = pk8_fp4(f + 8);
    *(uint2*)(xr4 + (((size_t)b * N_TOK + m0 + ml) * DIM + d0 + dc) / 2) = pk.v;
    *(unsigned int*)&tile[ml][(t & 3) * 8] = pk.u[0];
    *(unsigned int*)&tile[ml][(t & 3) * 8 + 4] = pk.u[1];
    if (XBF) {
      *(u16x8*)(xbf + roff) = bfp.v[0];
      *(u16x8*)(xbf + roff + 8) = bfp.v[1];
    }
    ssp += __shfl_xor(ssp, 1);
    ssp += __shfl_xor(ssp, 2);
    if ((t & 3) == 0)
      sspart[((size_t)b * N_TOK + m0 + ml) * 16 + (d0 >> 6)] = ssp;
  }
  __syncthreads();
  {
    const int dl = t >> 2, mc = (t & 3) * 16;
    const int sh = (dl & 1) * 4, dby = dl >> 1;
    union { unsigned int u[2]; uint2 v; } o;
    o.u[0] = o.u[1] = 0;
    #pragma unroll
    for (int jj = 0; jj < 8; ++jj) {
      const unsigned int b0 = ((unsigned int)tile[mc + 2 * jj][dby] >> sh) & 15u;
      const unsigned int b1 = ((unsigned int)tile[mc + 2 * jj + 1][dby] >> sh) & 15u;
      o.u[jj >> 2] |= (b0 | (b1 << 4)) << ((jj & 3) * 8);
    }
    *(uint2*)(XT4 + (((size_t)b * DIM + d0 + dl) * (size_t)N_TOK + m0 + mc) / 2) = o.v;
  }
}

// ---------------- GEMM A: Sraw = wn4(fp4) . xr4(fp4)^T ; P = exp(S*winv*xinv) ----------------

__global__ __launch_bounds__(256, 4) void kA(
    const unsigned char* __restrict__ wn4, const unsigned char* __restrict__ xr4,
    const float* __restrict__ winv, const float* __restrict__ sspart,
    unsigned char* __restrict__ Pp, float* __restrict__ pden, int Mc, int c0) {
  __shared__ __align__(16) unsigned char sA[16384];
  __shared__ __align__(16) unsigned char sB[16384];
  __shared__ float pd[128][2];
  __shared__ float winv_s[128], xinv_s[128];

  const int t = threadIdx.x, l = t & 63, w = t >> 6;
  const int wr = w >> 1, wc = w & 1;

  // T1: chunked XCD swizzle (grid (16, Mc/128, 8); nwg % 8 == 0 -> bijective).
  const int gy = Mc >> 7;
  const int nwg = 16 * gy * 8;
  const int lin = blockIdx.x + 16 * (blockIdx.y + gy * blockIdx.z);
  const int wg = (lin & 7) * (nwg >> 3) + (lin >> 3);
  const int xx = wg & 15, yy = (wg >> 4) % gy, zz = (wg >> 4) / gy;

  const int q0 = xx * 128;
  const int m0l = yy * 128;
  const int b = zz;
  const int m0g = c0 + m0l;

  if (t < 128) {
    winv_s[t] = winv[q0 + t];
  } else {
    const float* p = sspart + ((size_t)b * N_TOK + m0g + (t - 128)) * 16;
    float s = 0.0f;
    #pragma unroll
    for (int k = 0; k < 16; ++k) s += p[k];
    xinv_s[t - 128] = rsqrtf(fmaxf(s, 1e-24f));
  }

  f4 acc[4][4];
  #pragma unroll
  for (int i = 0; i < 4; ++i)
    #pragma unroll
    for (int j = 0; j < 4; ++j) acc[i][j] = (f4)0.0f;

  gemm_fp4(sA, sB,
           wn4 + (size_t)q0 * (DIM / 2), DIM / 2,
           xr4 + ((size_t)b * N_TOK + m0g) * (DIM / 2), DIM / 2,
           DIM / 256, w, l, wr, wc, acc);

  // epilogue: S = Sraw*winv*xinv in [-1,1]; P = exp(S) fp8 + row sums
  float ra[4][4];
  #pragma unroll
  for (int i = 0; i < 4; ++i)
    #pragma unroll
    for (int e = 0; e < 4; ++e) ra[i][e] = 0.0f;

  #pragma unroll
  for (int j = 0; j < 4; ++j) {
    const int cl = wc * 64 + j * 16 + (l & 15);  // local m col
    const float xv = xinv_s[cl];
    #pragma unroll
    for (int i = 0; i < 4; ++i)
      #pragma unroll
      for (int e = 0; e < 4; ++e) {
        const int row = wr * 64 + i * 16 + (l >> 4) * 4 + e;  // local q
        const float p = __expf(acc[i][j][e] * winv_s[row] * xv);
        ra[i][e] += p;
        Pp[((size_t)b * N_TOK + q0 + row) * (size_t)Mc + m0l + cl] = fp8_1(p);
      }
  }
  #pragma unroll
  for (int i = 0; i < 4; ++i)
    #pragma unroll
    for (int e = 0; e < 4; ++e) {
      float s = ra[i][e];
      s += __shfl_xor(s, 1); s += __shfl_xor(s, 2);
      s += __shfl_xor(s, 4); s += __shfl_xor(s, 8);
      if ((l & 15) == 0) pd[wr * 64 + i * 16 + (l >> 4) * 4 + e][wc] = s;
    }
  __syncthreads();
  if (t < 128)
    pden[((size_t)b * N_TOK + q0 + t) * 16 + (c0 >> 7) + yy] = pd[t][0] + pd[t][1];
}

// ---------------- GEMM B: O += P(fp8) . XT4(fp4)^T ; FINAL applies 1/den (bf16 if OBF) ----------------

template <int ACC, int FINAL, int OBF>
__global__ __launch_bounds__(256, 3) void kB(const unsigned char* __restrict__ Pp,
    const unsigned char* __restrict__ XT4, const float* __restrict__ pden,
    float* __restrict__ of32, unsigned short* __restrict__ obf, int Mc, int c0) {
  __shared__ __align__(16) unsigned char sA0[16384];
  __shared__ __align__(16) unsigned char sA1[16384];
  __shared__ __align__(16) unsigned char sB[16384];
  __shared__ float rden_s[128];

  const int t = threadIdx.x, l = t & 63, w = t >> 6;
  const int wr = w >> 1, wc = w & 1;

  // T1: chunked XCD swizzle, d0-INNER within XCD (P q-panel co-resident in L2).
  const int lin = blockIdx.x + 16 * (blockIdx.y + 8 * blockIdx.z);
  const int wg = (lin & 7) * 128 + (lin >> 3);
  const int s = wg & 127;
  const int d0 = (s & 7) * 128;
  const int q0 = (s >> 3) * 128;
  const int b = wg >> 7;

  f4 acc[4][4];
  #pragma unroll
  for (int i = 0; i < 4; ++i)
    #pragma unroll
    for (int j = 0; j < 4; ++j) acc[i][j] = (f4)0.0f;

  gemm_mixed(sA0, sA1, sB,
             Pp + ((size_t)b * N_TOK + q0) * (size_t)Mc, (size_t)Mc,
             XT4 + (((size_t)b * DIM + d0) * (size_t)N_TOK + c0) / 2, N_TOK / 2,
             Mc / 256, w, l, wr, wc, acc);

  if (FINAL) {
    if (t < 128) {
      const float* pp = pden + ((size_t)b * N_TOK + q0 + t) * 16;
      float ss = 0.0f;
      #pragma unroll
      for (int i = 0; i < 16; ++i) ss += pp[i];
      rden_s[t] = 1.0f / ss;
    }
    __syncthreads();
  }

  #pragma unroll
  for (int j = 0; j < 4; ++j) {
    const int cc = d0 + wc * 64 + j * 16 + (l & 15);
    #pragma unroll
    for (int i = 0; i < 4; ++i)
      #pragma unroll
      for (int e = 0; e < 4; ++e) {
        const int rl = wr * 64 + i * 16 + (l >> 4) * 4 + e;
        const size_t oi = (size_t)(q0 + rl) * (BATCH * DIM) + (size_t)b * DIM + cc;
        float v = acc[i][j][e];
        if (ACC) v += of32[oi];
        if (FINAL) {
          v *= rden_s[rl];
          if (OBF) { obf[oi] = f2bf(v); continue; }
        }
        of32[oi] = v;
      }
  }
}

// ---------------- final: out = LN(O + x) * gamma + beta ----------------

template <int OBF, int XBF>
__global__ __launch_bounds__(256) void kLN(const float* __restrict__ gamma,
    const float* __restrict__ beta, const unsigned short* __restrict__ obf,
    const float* __restrict__ of32, const unsigned short* __restrict__ xbf,
    const float* __restrict__ x, float* __restrict__ out) {
  __shared__ float sb[8];
  const int r = blockIdx.x;            // r = n*8 + b
  const int t = threadIdx.x;

  const size_t base = (size_t)r * DIM + t * 4;
  float o0, o1, o2, o3, x0, x1, x2, x3;
  if (OBF) {
    const ushort4 u = *(const ushort4*)(obf + base);
    o0 = bf2f(u.x); o1 = bf2f(u.y); o2 = bf2f(u.z); o3 = bf2f(u.w);
  } else {
    const float4 o4 = *(const float4*)(of32 + base);
    o0 = o4.x; o1 = o4.y; o2 = o4.z; o3 = o4.w;
  }
  if (XBF) {
    const ushort4 u = *(const ushort4*)(xbf + base);
    x0 = bf2f(u.x); x1 = bf2f(u.y); x2 = bf2f(u.z); x3 = bf2f(u.w);
  } else {
    const float4 x4 = *(const float4*)(x + base);
    x0 = x4.x; x1 = x4.y; x2 = x4.z; x3 = x4.w;
  }
  const float y0 = o0 + x0, y1 = o1 + x1, y2 = o2 + x2, y3 = o3 + x3;

  float s1 = y0 + y1 + y2 + y3;
  float s2 = y0 * y0 + y1 * y1 + y2 * y2 + y3 * y3;
  #pragma unroll
  for (int o = 32; o; o >>= 1) { s1 += __shfl_xor(s1, o); s2 += __shfl_xor(s2, o); }
  if ((t & 63) == 0) { sb[t >> 6] = s1; sb[4 + (t >> 6)] = s2; }
  __syncthreads();
  s1 = sb[0] + sb[1] + sb[2] + sb[3];
  s2 = sb[4] + sb[5] + sb[6] + sb[7];

  const float mean = s1 * (1.0f / DIM);
  const float var = s2 * (1.0f / DIM) - mean * mean;
  const float rstd = rsqrtf(var + 1e-5f);

  const float4 g4 = *(const float4*)(gamma + t * 4);
  const float4 b4 = *(const float4*)(beta + t * 4);
  float4 rr;
  rr.x = (y0 - mean) * rstd * g4.x + b4.x;
  rr.y = (y1 - mean) * rstd * g4.y + b4.y;
  rr.z = (y2 - mean) * rstd * g4.z + b4.z;
  rr.w = (y3 - mean) * rstd * g4.w + b4.w;
  *(float4*)(out + (size_t)r * DIM + t * 4) = rr;
}

// ---------------- launch ----------------

extern "C" void kernel_launch(void* const* d_in, const int* in_sizes, int n_in,
                              void* d_out, int out_size, void* d_ws, size_t ws_size,
                              hipStream_t stream) {
  (void)in_sizes; (void)n_in; (void)out_size;
  const float* x     = (const float*)d_in[0];
  const float* embed = (const float*)d_in[1];
  const float* gamma = (const float*)d_in[2];
  const float* beta  = (const float*)d_in[3];
  float* out = (float*)d_out;

  size_t off = 0;
  char* ws = (char*)d_ws;
  auto take = [&](size_t bytes) { char* p = ws + off; off += bytes; return p; };
  unsigned char* XT4  = (unsigned char*)take((size_t)BATCH * DIM * N_TOK / 2);  //  8.4 MB
  unsigned char* xr4  = (unsigned char*)take((size_t)BATCH * N_TOK * DIM / 2);  //  8.4 MB
  unsigned char* wn4  = (unsigned char*)take((size_t)N_TOK * DIM / 2);          //  1.0 MB
  float* winv   = (float*)take((size_t)N_TOK * 4);                              //  8 KB
  float* sspart = (float*)take((size_t)BATCH * N_TOK * 16 * 4);                 //  2.1 MB
  float* pden   = (float*)take((size_t)BATCH * N_TOK * 16 * 4);                 //  2.1 MB
  const size_t fixed = off;

  int Mc = 2048;
  while (Mc > 256 && fixed + (size_t)BATCH * N_TOK * Mc > ws_size) Mc >>= 1;
  unsigned char* Pp = (unsigned char*)take((size_t)BATCH * N_TOK * Mc);         // 33.6 MB full

  const size_t half = (size_t)N_TOK * BATCH * DIM * 2;                          // 33.6 MB
  const int use_obf = (off + half <= ws_size) ? 1 : 0;
  unsigned short* obf = use_obf ? (unsigned short*)take(half) : (unsigned short*)out;
  const int use_xbf = (off + half <= ws_size) ? 1 : 0;
  unsigned short* xbf = use_xbf ? (unsigned short*)take(half) : (unsigned short*)out;

  prep_wn<<<N_TOK, 256, 0, stream>>>(embed, wn4, winv);
  if (use_xbf)
    prep_x<1><<<dim3(N_TOK / 64, DIM / 64, BATCH), 256, 0, stream>>>(x, xr4, XT4, xbf, sspart);
  else
    prep_x<0><<<dim3(N_TOK / 64, DIM / 64, BATCH), 256, 0, stream>>>(x, xr4, XT4, xbf, sspart);

  const int nchunk = N_TOK / Mc;
  for (int ci = 0; ci < nchunk; ++ci) {
    const int c0 = ci * Mc;
    kA<<<dim3(16, Mc / 128, BATCH), 256, 0, stream>>>(wn4, xr4, winv, sspart, Pp, pden, Mc, c0);
    const bool first = (ci == 0), last = (ci == nchunk - 1);
    const dim3 gB(16, 8, BATCH);
    if (last) {
      if (use_obf) {
        if (first) kB<0, 1, 1><<<gB, 256, 0, stream>>>(Pp, XT4, pden, out, obf, Mc, c0);
        else       kB<1, 1, 1><<<gB, 256, 0, stream>>>(Pp, XT4, pden, out, obf, Mc, c0);
      } else {
        if (first) kB<0, 1, 0><<<gB, 256, 0, stream>>>(Pp, XT4, pden, out, obf, Mc, c0);
        else       kB<1, 1, 0><<<gB, 256, 0, stream>>>(Pp, XT4, pden, out, obf, Mc, c0);
      }
    } else {
      if (first) kB<0, 0, 0><<<gB, 256, 0, stream>>>(Pp, XT4, pden, out, obf, Mc, c0);
      else       kB<1, 0, 0><<<gB, 256, 0, stream>>>(Pp, XT4, pden, out, obf, Mc, c0);
    }
  }
  if (use_obf) {
    if (use_xbf) kLN<1, 1><<<N_TOK * BATCH, 256, 0, stream>>>(gamma, beta, obf, out, xbf, x, out);
    else         kLN<1, 0><<<N_TOK * BATCH, 256, 0, stream>>>(gamma, beta, obf, out, xbf, x, out);
  } else {
    if (use_xbf) kLN<0, 1><<<N_TOK * BATCH, 256, 0, stream>>>(gamma, beta, obf, out, xbf, x, out);
    else         kLN<0, 0><<<N_TOK * BATCH, 256, 0, stream>>>(gamma, beta, obf, out, xbf, x, out);
  }
}

// Round 17
// 123.936 us; speedup vs baseline: 3.2457x; 1.0118x over previous
//
#include <hip/hip_runtime.h>
#include <hip/hip_bf16.h>

typedef float f4 __attribute__((ext_vector_type(4)));
typedef int i32x4 __attribute__((ext_vector_type(4)));
typedef int i32x8 __attribute__((ext_vector_type(8)));
typedef unsigned char u8x16 __attribute__((ext_vector_type(16)));
typedef unsigned short u16x8 __attribute__((ext_vector_type(8)));

#define N_TOK 2048
#define BATCH 8
#define DIM   1024

#if defined(__has_builtin)
#if __has_builtin(__builtin_amdgcn_cvt_scalef32_pk_fp4_f32)
#define HAS_FP4_CVT 1
#endif
#endif

// ---- fp8 e4m3 (OCP) pack helpers ----
static __device__ __forceinline__ unsigned char fp8_1(float a) {
  return (unsigned char)(__builtin_amdgcn_cvt_pk_fp8_f32(a, a, 0, false) & 0xFF);
}
// f32 -> bf16 rne
static __device__ __forceinline__ unsigned short f2bf(float f) {
  unsigned int b = __float_as_uint(f);
  b += 0x7FFFu + ((b >> 16) & 1u);
  return (unsigned short)(b >> 16);
}
static __device__ __forceinline__ float bf2f(unsigned short u) {
  return __uint_as_float(((unsigned int)u) << 16);
}
// fp4 e2m1 encode fallback ladder.  Codes: 0,.5,1,1.5,2,3,4,6 (+sign bit 3).
static __device__ __forceinline__ unsigned int fp4_enc(float v) {
  const float a = fabsf(v);
  unsigned int c = (a >= 0.25f) + (a >= 0.75f) + (a >= 1.25f) + (a >= 1.75f)
                 + (a >= 2.5f) + (a >= 3.5f) + (a >= 5.0f);
  return c | (v < 0.0f ? 8u : 0u);
}
// pack 8 f32 -> 8 fp4 nibbles (low nibble = v[0]); HW cvt when available
static __device__ __forceinline__ unsigned int pk8_fp4(const float* v) {
#ifdef HAS_FP4_CVT
  unsigned int r = 0;
  r = __builtin_amdgcn_cvt_scalef32_pk_fp4_f32(r, v[0], v[1], 1.0f, 0);
  r = __builtin_amdgcn_cvt_scalef32_pk_fp4_f32(r, v[2], v[3], 1.0f, 1);
  r = __builtin_amdgcn_cvt_scalef32_pk_fp4_f32(r, v[4], v[5], 1.0f, 2);
  r = __builtin_amdgcn_cvt_scalef32_pk_fp4_f32(r, v[6], v[7], 1.0f, 3);
  return r;
#else
  unsigned int r = 0;
  #pragma unroll
  for (int i = 0; i < 8; ++i) r |= fp4_enc(v[i]) << (i * 4);
  return r;
#endif
}

static __device__ __forceinline__ void gld16(const void* g, void* lds) {
  __builtin_amdgcn_global_load_lds(
      (const __attribute__((address_space(1))) unsigned int*)g,
      (__attribute__((address_space(3))) unsigned int*)lds, 16, 0, 0);
}

// Stage a [128 rows x 128 byte] tile into 16 KB LDS with 256 threads
// (4 x gld16 each).  Linear LDS dest, XOR-swizzled per-lane global source
// (G21): LDS[row*128 + (g16 ^ ((row&7)<<4))] = G[row][g16] per 16B granule.
static __device__ __forceinline__ void stage_tile(const unsigned char* g, size_t ldb,
                                                  unsigned char* lds, int w, int l) {
  const int rgrp = l >> 3;                       // row within 8-row granule
  const int srcb = (((l & 7) ^ rgrp) << 4);      // swizzled byte offset in row
  #pragma unroll
  for (int gi = 0; gi < 4; ++gi) {
    int rb = (gi * 4 + w) * 8;                   // wave-granule base row
    gld16(g + (size_t)(rb + rgrp) * ldb + srcb, lds + (gi * 4 + w) * 1024);
  }
}

// 32B fp8 fragment (K=128): two 16B granules, swizzle-aware.  kb 32B-aligned.
static __device__ __forceinline__ i32x8 fragld32(const unsigned char* lds, int row, int kb) {
  const unsigned char* base = lds + row * 128;
  const int swz = (row & 7) << 4;
  const i32x4 lo = *(const i32x4*)(base + (kb ^ swz));
  const i32x4 hi = *(const i32x4*)(base + ((kb + 16) ^ swz));
  i32x8 r;
  r[0] = lo[0]; r[1] = lo[1]; r[2] = lo[2]; r[3] = lo[3];
  r[4] = hi[0]; r[5] = hi[1]; r[6] = hi[2]; r[7] = hi[3];
  return r;
}
// 16B fp4 fragment (K=128 at 4 bit): one granule, data in regs 0-3.
static __device__ __forceinline__ i32x8 fragld16(const unsigned char* lds, int row, int kb) {
  const i32x4 lo = *(const i32x4*)(lds + row * 128 + (kb ^ ((row & 7) << 4)));
  i32x8 r;
  r[0] = lo[0]; r[1] = lo[1]; r[2] = lo[2]; r[3] = lo[3];
  r[4] = 0; r[5] = 0; r[6] = 0; r[7] = 0;
  return r;
}

// fp4 x fp4 MX K-loop (kA): BK=256, TWO 16KB tiles staged, 2 substeps of
// 16 mfma_scale K=128.  cbsz=blgp=4 (fp4), scale 0x7F = 1.0 exact.
static __device__ __forceinline__ void gemm_fp4(unsigned char* sA, unsigned char* sB,
    const unsigned char* Ab, size_t lda, const unsigned char* Bb, size_t ldb,
    int nko, int w, int l, int wr, int wc, f4 acc[4][4]) {
  for (int kk = 0; kk < nko; ++kk) {
    stage_tile(Ab + (size_t)kk * 128, lda, sA, w, l);
    stage_tile(Bb + (size_t)kk * 128, ldb, sB, w, l);
    __syncthreads();
    #pragma unroll
    for (int ks = 0; ks < 2; ++ks) {
      const int kb = ks * 64 + (l >> 4) * 16;
      i32x8 af[4], bf[4];
      #pragma unroll
      for (int i = 0; i < 4; ++i)
        af[i] = fragld16(sA, wr * 64 + i * 16 + (l & 15), kb);
      #pragma unroll
      for (int j = 0; j < 4; ++j)
        bf[j] = fragld16(sB, wc * 64 + j * 16 + (l & 15), kb);
      #pragma unroll
      for (int i = 0; i < 4; ++i)
        #pragma unroll
        for (int j = 0; j < 4; ++j)
          acc[i][j] = __builtin_amdgcn_mfma_scale_f32_16x16x128_f8f6f4(
              af[i], bf[j], acc[i][j], 4, 4, 0, 0x7F7F7F7F, 0, 0x7F7F7F7F);
    }
    __syncthreads();
  }
}

// Mixed-format MX K-loop (kB): A fp8 (cbsz=0), B fp4 (blgp=4), BK=256.
static __device__ __forceinline__ void gemm_mixed(unsigned char* sA0, unsigned char* sA1,
    unsigned char* sB, const unsigned char* Ab, size_t lda,
    const unsigned char* Bb, size_t ldb, int nko, int w, int l, int wr, int wc,
    f4 acc[4][4]) {
  for (int kk = 0; kk < nko; ++kk) {
    stage_tile(Ab + (size_t)kk * 256, lda, sA0, w, l);
    stage_tile(Ab + (size_t)kk * 256 + 128, lda, sA1, w, l);
    stage_tile(Bb + (size_t)kk * 128, ldb, sB, w, l);
    __syncthreads();
    #pragma unroll
    for (int ks = 0; ks < 2; ++ks) {
      const unsigned char* sA = ks ? sA1 : sA0;
      const int kbA = (l >> 4) * 32;
      const int kbB = ks * 64 + (l >> 4) * 16;
      i32x8 af[4], bf[4];
      #pragma unroll
      for (int i = 0; i < 4; ++i)
        af[i] = fragld32(sA, wr * 64 + i * 16 + (l & 15), kbA);
      #pragma unroll
      for (int j = 0; j < 4; ++j)
        bf[j] = fragld16(sB, wc * 64 + j * 16 + (l & 15), kbB);
      #pragma unroll
      for (int i = 0; i < 4; ++i)
        #pragma unroll
        for (int j = 0; j < 4; ++j)
          acc[i][j] = __builtin_amdgcn_mfma_scale_f32_16x16x128_f8f6f4(
              af[i], bf[j], acc[i][j], 0, 4, 0, 0x7F7F7F7F, 0, 0x7F7F7F7F);
    }
    __syncthreads();
  }
}

// ---------------- prep kernels ----------------

static __device__ __forceinline__ float block_reduce_sum(float v, volatile float* sb, int t) {
  #pragma unroll
  for (int o = 32; o; o >>= 1) v += __shfl_xor(v, o);
  if ((t & 63) == 0) sb[t >> 6] = v;
  __syncthreads();
  float r = sb[0] + sb[1] + sb[2] + sb[3];
  __syncthreads();
  return r;
}

// embed -> RAW fp4 wn4 (adjacent-d nibble pairs, matching xr4) + winv[n]
__global__ __launch_bounds__(256) void prep_wn(const float* __restrict__ e,
                                               unsigned char* __restrict__ wn4,
                                               float* __restrict__ winv) {
  __shared__ float sb[4];
  const int n = blockIdx.x, t = threadIdx.x;
  const float4 v = *(const float4*)(e + (size_t)n * DIM + t * 4);
  float ss = v.x * v.x + v.y * v.y + v.z * v.z + v.w * v.w;
  ss = block_reduce_sum(ss, sb, t);
  if (t == 0) winv[n] = rsqrtf(fmaxf(ss, 1e-24f));
  float f[8];
  f[0] = v.x; f[1] = v.y; f[2] = v.z; f[3] = v.w;
  f[4] = 0.0f; f[5] = 0.0f; f[6] = 0.0f; f[7] = 0.0f;
  *(unsigned short*)(wn4 + ((size_t)n * DIM + t * 4) / 2) =
      (unsigned short)(pk8_fp4(f) & 0xFFFFu);
}

// Fused x pass (reads x ONCE), 4x m-COARSENED (R17): each block handles
// 256 m x 64 d.  Phase 1: 4 unrolled sub-tiles (16 independent float4 loads
// in flight -> HBM latency amortized); emits xr4 + optional xbf + sspart and
// packed codes to LDS.  Phase 2: transpose; each thread emits 32 contiguous
// bytes of XT4 (two uint4 stores; 4 lanes/dl -> 128 B lines).
template <int XBF>
__global__ __launch_bounds__(256) void prep_x(const float* __restrict__ x,
    unsigned char* __restrict__ xr4, unsigned char* __restrict__ XT4,
    unsigned short* __restrict__ xbf, float* __restrict__ sspart) {
  __shared__ unsigned char tile[256][36];   // packed fp4 pairs along d
  const int t = threadIdx.x;
  const int m0 = blockIdx.x * 256, d0 = blockIdx.y * 64, b = blockIdx.z;
  #pragma unroll
  for (int mi = 0; mi < 4; ++mi) {
    const int ml = mi * 64 + (t >> 2), dc = (t & 3) * 16;
    const size_t roff = ((size_t)(m0 + ml) * BATCH + b) * DIM + d0 + dc;
    const float* row = x + roff;
    float f[16];
    union { unsigned short u[16]; u16x8 v[2]; } bfp;
    float ssp = 0.0f;
    #pragma unroll
    for (int i = 0; i < 4; ++i) {
      float4 v = *(const float4*)(row + i * 4);
      ssp += v.x * v.x + v.y * v.y + v.z * v.z + v.w * v.w;
      f[i * 4 + 0] = v.x; f[i * 4 + 1] = v.y;
      f[i * 4 + 2] = v.z; f[i * 4 + 3] = v.w;
      if (XBF) {
        bfp.u[i * 4 + 0] = f2bf(v.x); bfp.u[i * 4 + 1] = f2bf(v.y);
        bfp.u[i * 4 + 2] = f2bf(v.z); bfp.u[i * 4 + 3] = f2bf(v.w);
      }
    }
    union { unsigned int u[2]; uint2 v; } pk;
    pk.u[0] = pk8_fp4(f);
    pk.u[1] = pk8_fp4(f + 8);
    *(uint2*)(xr4 + (((size_t)b * N_TOK + m0 + ml) * DIM + d0 + dc) / 2) = pk.v;
    *(unsigned int*)&tile[ml][(t & 3) * 8] = pk.u[0];
    *(unsigned int*)&tile[ml][(t & 3) * 8 + 4] = pk.u[1];
    if (XBF) {
      *(u16x8*)(xbf + roff) = bfp.v[0];
      *(u16x8*)(xbf + roff + 8) = bfp.v[1];
    }
    ssp += __shfl_xor(ssp, 1);
    ssp += __shfl_xor(ssp, 2);
    if ((t & 3) == 0)
      sspart[((size_t)b * N_TOK + m0 + ml) * 16 + (d0 >> 6)] = ssp;
  }
  __syncthreads();
  {
    const int dl = t >> 2, lane = t & 3;
    const int sh = (dl & 1) * 4, dby = dl >> 1;
    union { unsigned int u[8]; uint4 v[2]; } o;
    #pragma unroll
    for (int k = 0; k < 8; ++k) o.u[k] = 0;
    #pragma unroll
    for (int jj = 0; jj < 32; ++jj) {
      const int m = lane * 64 + 2 * jj;
      const unsigned int b0 = ((unsigned int)tile[m][dby] >> sh) & 15u;
      const unsigned int b1 = ((unsigned int)tile[m + 1][dby] >> sh) & 15u;
      o.u[jj >> 2] |= (b0 | (b1 << 4)) << ((jj & 3) * 8);
    }
    unsigned char* dst =
        XT4 + (((size_t)b * DIM + d0 + dl) * (size_t)N_TOK + m0 + lane * 64) / 2;
    *(uint4*)dst = o.v[0];
    *(uint4*)(dst + 16) = o.v[1];
  }
}

// ---------------- GEMM A: Sraw = wn4(fp4) . xr4(fp4)^T ; P = exp(S*winv*xinv) ----------------

__global__ __launch_bounds__(256, 4) void kA(
    const unsigned char* __restrict__ wn4, const unsigned char* __restrict__ xr4,
    const float* __restrict__ winv, const float* __restrict__ sspart,
    unsigned char* __restrict__ Pp, float* __restrict__ pden, int Mc, int c0) {
  __shared__ __align__(16) unsigned char sA[16384];
  __shared__ __align__(16) unsigned char sB[16384];
  __shared__ float pd[128][2];
  __shared__ float winv_s[128], xinv_s[128];

  const int t = threadIdx.x, l = t & 63, w = t >> 6;
  const int wr = w >> 1, wc = w & 1;

  // T1: chunked XCD swizzle (grid (16, Mc/128, 8); nwg % 8 == 0 -> bijective).
  const int gy = Mc >> 7;
  const int nwg = 16 * gy * 8;
  const int lin = blockIdx.x + 16 * (blockIdx.y + gy * blockIdx.z);
  const int wg = (lin & 7) * (nwg >> 3) + (lin >> 3);
  const int xx = wg & 15, yy = (wg >> 4) % gy, zz = (wg >> 4) / gy;

  const int q0 = xx * 128;
  const int m0l = yy * 128;
  const int b = zz;
  const int m0g = c0 + m0l;

  if (t < 128) {
    winv_s[t] = winv[q0 + t];
  } else {
    const float* p = sspart + ((size_t)b * N_TOK + m0g + (t - 128)) * 16;
    float s = 0.0f;
    #pragma unroll
    for (int k = 0; k < 16; ++k) s += p[k];
    xinv_s[t - 128] = rsqrtf(fmaxf(s, 1e-24f));
  }

  f4 acc[4][4];
  #pragma unroll
  for (int i = 0; i < 4; ++i)
    #pragma unroll
    for (int j = 0; j < 4; ++j) acc[i][j] = (f4)0.0f;

  gemm_fp4(sA, sB,
           wn4 + (size_t)q0 * (DIM / 2), DIM / 2,
           xr4 + ((size_t)b * N_TOK + m0g) * (DIM / 2), DIM / 2,
           DIM / 256, w, l, wr, wc, acc);

  // epilogue: S = Sraw*winv*xinv in [-1,1]; P = exp(S) fp8 + row sums
  float ra[4][4];
  #pragma unroll
  for (int i = 0; i < 4; ++i)
    #pragma unroll
    for (int e = 0; e < 4; ++e) ra[i][e] = 0.0f;

  #pragma unroll
  for (int j = 0; j < 4; ++j) {
    const int cl = wc * 64 + j * 16 + (l & 15);  // local m col
    const float xv = xinv_s[cl];
    #pragma unroll
    for (int i = 0; i < 4; ++i)
      #pragma unroll
      for (int e = 0; e < 4; ++e) {
        const int row = wr * 64 + i * 16 + (l >> 4) * 4 + e;  // local q
        const float p = __expf(acc[i][j][e] * winv_s[row] * xv);
        ra[i][e] += p;
        Pp[((size_t)b * N_TOK + q0 + row) * (size_t)Mc + m0l + cl] = fp8_1(p);
      }
  }
  #pragma unroll
  for (int i = 0; i < 4; ++i)
    #pragma unroll
    for (int e = 0; e < 4; ++e) {
      float s = ra[i][e];
      s += __shfl_xor(s, 1); s += __shfl_xor(s, 2);
      s += __shfl_xor(s, 4); s += __shfl_xor(s, 8);
      if ((l & 15) == 0) pd[wr * 64 + i * 16 + (l >> 4) * 4 + e][wc] = s;
    }
  __syncthreads();
  if (t < 128)
    pden[((size_t)b * N_TOK + q0 + t) * 16 + (c0 >> 7) + yy] = pd[t][0] + pd[t][1];
}

// ---------------- GEMM B: O += P(fp8) . XT4(fp4)^T ; FINAL applies 1/den (bf16 if OBF) ----------------

template <int ACC, int FINAL, int OBF>
__global__ __launch_bounds__(256, 3) void kB(const unsigned char* __restrict__ Pp,
    const unsigned char* __restrict__ XT4, const float* __restrict__ pden,
    float* __restrict__ of32, unsigned short* __restrict__ obf, int Mc, int c0) {
  __shared__ __align__(16) unsigned char sA0[16384];
  __shared__ __align__(16) unsigned char sA1[16384];
  __shared__ __align__(16) unsigned char sB[16384];
  __shared__ float rden_s[128];

  const int t = threadIdx.x, l = t & 63, w = t >> 6;
  const int wr = w >> 1, wc = w & 1;

  // T1: chunked XCD swizzle, d0-INNER within XCD (P q-panel co-resident in L2).
  const int lin = blockIdx.x + 16 * (blockIdx.y + 8 * blockIdx.z);
  const int wg = (lin & 7) * 128 + (lin >> 3);
  const int s = wg & 127;
  const int d0 = (s & 7) * 128;
  const int q0 = (s >> 3) * 128;
  const int b = wg >> 7;

  f4 acc[4][4];
  #pragma unroll
  for (int i = 0; i < 4; ++i)
    #pragma unroll
    for (int j = 0; j < 4; ++j) acc[i][j] = (f4)0.0f;

  gemm_mixed(sA0, sA1, sB,
             Pp + ((size_t)b * N_TOK + q0) * (size_t)Mc, (size_t)Mc,
             XT4 + (((size_t)b * DIM + d0) * (size_t)N_TOK + c0) / 2, N_TOK / 2,
             Mc / 256, w, l, wr, wc, acc);

  if (FINAL) {
    if (t < 128) {
      const float* pp = pden + ((size_t)b * N_TOK + q0 + t) * 16;
      float ss = 0.0f;
      #pragma unroll
      for (int i = 0; i < 16; ++i) ss += pp[i];
      rden_s[t] = 1.0f / ss;
    }
    __syncthreads();
  }

  #pragma unroll
  for (int j = 0; j < 4; ++j) {
    const int cc = d0 + wc * 64 + j * 16 + (l & 15);
    #pragma unroll
    for (int i = 0; i < 4; ++i)
      #pragma unroll
      for (int e = 0; e < 4; ++e) {
        const int rl = wr * 64 + i * 16 + (l >> 4) * 4 + e;
        const size_t oi = (size_t)(q0 + rl) * (BATCH * DIM) + (size_t)b * DIM + cc;
        float v = acc[i][j][e];
        if (ACC) v += of32[oi];
        if (FINAL) {
          v *= rden_s[rl];
          if (OBF) { obf[oi] = f2bf(v); continue; }
        }
        of32[oi] = v;
      }
  }
}

// ---------------- final: out = LN(O + x) * gamma + beta ----------------

template <int OBF, int XBF>
__global__ __launch_bounds__(256) void kLN(const float* __restrict__ gamma,
    const float* __restrict__ beta, const unsigned short* __restrict__ obf,
    const float* __restrict__ of32, const unsigned short* __restrict__ xbf,
    const float* __restrict__ x, float* __restrict__ out) {
  __shared__ float sb[8];
  const int r = blockIdx.x;            // r = n*8 + b
  const int t = threadIdx.x;

  const size_t base = (size_t)r * DIM + t * 4;
  float o0, o1, o2, o3, x0, x1, x2, x3;
  if (OBF) {
    const ushort4 u = *(const ushort4*)(obf + base);
    o0 = bf2f(u.x); o1 = bf2f(u.y); o2 = bf2f(u.z); o3 = bf2f(u.w);
  } else {
    const float4 o4 = *(const float4*)(of32 + base);
    o0 = o4.x; o1 = o4.y; o2 = o4.z; o3 = o4.w;
  }
  if (XBF) {
    const ushort4 u = *(const ushort4*)(xbf + base);
    x0 = bf2f(u.x); x1 = bf2f(u.y); x2 = bf2f(u.z); x3 = bf2f(u.w);
  } else {
    const float4 x4 = *(const float4*)(x + base);
    x0 = x4.x; x1 = x4.y; x2 = x4.z; x3 = x4.w;
  }
  const float y0 = o0 + x0, y1 = o1 + x1, y2 = o2 + x2, y3 = o3 + x3;

  float s1 = y0 + y1 + y2 + y3;
  float s2 = y0 * y0 + y1 * y1 + y2 * y2 + y3 * y3;
  #pragma unroll
  for (int o = 32; o; o >>= 1) { s1 += __shfl_xor(s1, o); s2 += __shfl_xor(s2, o); }
  if ((t & 63) == 0) { sb[t >> 6] = s1; sb[4 + (t >> 6)] = s2; }
  __syncthreads();
  s1 = sb[0] + sb[1] + sb[2] + sb[3];
  s2 = sb[4] + sb[5] + sb[6] + sb[7];

  const float mean = s1 * (1.0f / DIM);
  const float var = s2 * (1.0f / DIM) - mean * mean;
  const float rstd = rsqrtf(var + 1e-5f);

  const float4 g4 = *(const float4*)(gamma + t * 4);
  const float4 b4 = *(const float4*)(beta + t * 4);
  float4 rr;
  rr.x = (y0 - mean) * rstd * g4.x + b4.x;
  rr.y = (y1 - mean) * rstd * g4.y + b4.y;
  rr.z = (y2 - mean) * rstd * g4.z + b4.z;
  rr.w = (y3 - mean) * rstd * g4.w + b4.w;
  *(float4*)(out + (size_t)r * DIM + t * 4) = rr;
}

// ---------------- launch ----------------

extern "C" void kernel_launch(void* const* d_in, const int* in_sizes, int n_in,
                              void* d_out, int out_size, void* d_ws, size_t ws_size,
                              hipStream_t stream) {
  (void)in_sizes; (void)n_in; (void)out_size;
  const float* x     = (const float*)d_in[0];
  const float* embed = (const float*)d_in[1];
  const float* gamma = (const float*)d_in[2];
  const float* beta  = (const float*)d_in[3];
  float* out = (float*)d_out;

  size_t off = 0;
  char* ws = (char*)d_ws;
  auto take = [&](size_t bytes) { char* p = ws + off; off += bytes; return p; };
  unsigned char* XT4  = (unsigned char*)take((size_t)BATCH * DIM * N_TOK / 2);  //  8.4 MB
  unsigned char* xr4  = (unsigned char*)take((size_t)BATCH * N_TOK * DIM / 2);  //  8.4 MB
  unsigned char* wn4  = (unsigned char*)take((size_t)N_TOK * DIM / 2);          //  1.0 MB
  float* winv   = (float*)take((size_t)N_TOK * 4);                              //  8 KB
  float* sspart = (float*)take((size_t)BATCH * N_TOK * 16 * 4);                 //  2.1 MB
  float* pden   = (float*)take((size_t)BATCH * N_TOK * 16 * 4);                 //  2.1 MB
  const size_t fixed = off;

  int Mc = 2048;
  while (Mc > 256 && fixed + (size_t)BATCH * N_TOK * Mc > ws_size) Mc >>= 1;
  unsigned char* Pp = (unsigned char*)take((size_t)BATCH * N_TOK * Mc);         // 33.6 MB full

  const size_t half = (size_t)N_TOK * BATCH * DIM * 2;                          // 33.6 MB
  const int use_obf = (off + half <= ws_size) ? 1 : 0;
  unsigned short* obf = use_obf ? (unsigned short*)take(half) : (unsigned short*)out;
  const int use_xbf = (off + half <= ws_size) ? 1 : 0;
  unsigned short* xbf = use_xbf ? (unsigned short*)take(half) : (unsigned short*)out;

  prep_wn<<<N_TOK, 256, 0, stream>>>(embed, wn4, winv);
  if (use_xbf)
    prep_x<1><<<dim3(N_TOK / 256, DIM / 64, BATCH), 256, 0, stream>>>(x, xr4, XT4, xbf, sspart);
  else
    prep_x<0><<<dim3(N_TOK / 256, DIM / 64, BATCH), 256, 0, stream>>>(x, xr4, XT4, xbf, sspart);

  const int nchunk = N_TOK / Mc;
  for (int ci = 0; ci < nchunk; ++ci) {
    const int c0 = ci * Mc;
    kA<<<dim3(16, Mc / 128, BATCH), 256, 0, stream>>>(wn4, xr4, winv, sspart, Pp, pden, Mc, c0);
    const bool first = (ci == 0), last = (ci == nchunk - 1);
    const dim3 gB(16, 8, BATCH);
    if (last) {
      if (use_obf) {
        if (first) kB<0, 1, 1><<<gB, 256, 0, stream>>>(Pp, XT4, pden, out, obf, Mc, c0);
        else       kB<1, 1, 1><<<gB, 256, 0, stream>>>(Pp, XT4, pden, out, obf, Mc, c0);
      } else {
        if (first) kB<0, 1, 0><<<gB, 256, 0, stream>>>(Pp, XT4, pden, out, obf, Mc, c0);
        else       kB<1, 1, 0><<<gB, 256, 0, stream>>>(Pp, XT4, pden, out, obf, Mc, c0);
      }
    } else {
      if (first) kB<0, 0, 0><<<gB, 256, 0, stream>>>(Pp, XT4, pden, out, obf, Mc, c0);
      else       kB<1, 0, 0><<<gB, 256, 0, stream>>>(Pp, XT4, pden, out, obf, Mc, c0);
    }
  }
  if (use_obf) {
    if (use_xbf) kLN<1, 1><<<N_TOK * BATCH, 256, 0, stream>>>(gamma, beta, obf, out, xbf, x, out);
    else         kLN<1, 0><<<N_TOK * BATCH, 256, 0, stream>>>(gamma, beta, obf, out, xbf, x, out);
  } else {
    if (use_xbf) kLN<0, 1><<<N_TOK * BATCH, 256, 0, stream>>>(gamma, beta, obf, out, xbf, x, out);
    else         kLN<0, 0><<<N_TOK * BATCH, 256, 0, stream>>>(gamma, beta, obf, out, xbf, x, out);
  }
}

// Round 18
// 121.320 us; speedup vs baseline: 3.3156x; 1.0216x over previous
//
#include <hip/hip_runtime.h>
#include <hip/hip_bf16.h>

typedef float f4 __attribute__((ext_vector_type(4)));
typedef int i32x4 __attribute__((ext_vector_type(4)));
typedef int i32x8 __attribute__((ext_vector_type(8)));
typedef unsigned short u16x4 __attribute__((ext_vector_type(4)));

#define N_TOK 2048
#define BATCH 8
#define DIM   1024

#if defined(__has_builtin)
#if __has_builtin(__builtin_amdgcn_cvt_scalef32_pk_fp4_f32)
#define HAS_FP4_CVT 1
#endif
#endif

// ---- fp8 e4m3 (OCP) pack helpers ----
static __device__ __forceinline__ unsigned char fp8_1(float a) {
  return (unsigned char)(__builtin_amdgcn_cvt_pk_fp8_f32(a, a, 0, false) & 0xFF);
}
// f32 -> bf16 rne
static __device__ __forceinline__ unsigned short f2bf(float f) {
  unsigned int b = __float_as_uint(f);
  b += 0x7FFFu + ((b >> 16) & 1u);
  return (unsigned short)(b >> 16);
}
static __device__ __forceinline__ float bf2f(unsigned short u) {
  return __uint_as_float(((unsigned int)u) << 16);
}
// fp4 e2m1 encode fallback ladder.  Codes: 0,.5,1,1.5,2,3,4,6 (+sign bit 3).
static __device__ __forceinline__ unsigned int fp4_enc(float v) {
  const float a = fabsf(v);
  unsigned int c = (a >= 0.25f) + (a >= 0.75f) + (a >= 1.25f) + (a >= 1.75f)
                 + (a >= 2.5f) + (a >= 3.5f) + (a >= 5.0f);
  return c | (v < 0.0f ? 8u : 0u);
}
// pack 4 f32 -> 4 fp4 nibbles in a u16 (low nibble = a); HW cvt when available
static __device__ __forceinline__ unsigned short pk4_fp4(float a, float b, float c, float d) {
#ifdef HAS_FP4_CVT
  unsigned int r = 0;
  r = __builtin_amdgcn_cvt_scalef32_pk_fp4_f32(r, a, b, 1.0f, 0);
  r = __builtin_amdgcn_cvt_scalef32_pk_fp4_f32(r, c, d, 1.0f, 1);
  return (unsigned short)(r & 0xFFFFu);
#else
  return (unsigned short)(fp4_enc(a) | (fp4_enc(b) << 4) |
                          (fp4_enc(c) << 8) | (fp4_enc(d) << 12));
#endif
}

static __device__ __forceinline__ void gld16(const void* g, void* lds) {
  __builtin_amdgcn_global_load_lds(
      (const __attribute__((address_space(1))) unsigned int*)g,
      (__attribute__((address_space(3))) unsigned int*)lds, 16, 0, 0);
}

// Stage a [128 rows x 128 byte] tile into 16 KB LDS with 256 threads
// (4 x gld16 each).  Linear LDS dest, XOR-swizzled per-lane global source
// (G21): LDS[row*128 + (g16 ^ ((row&7)<<4))] = G[row][g16] per 16B granule.
static __device__ __forceinline__ void stage_tile(const unsigned char* g, size_t ldb,
                                                  unsigned char* lds, int w, int l) {
  const int rgrp = l >> 3;                       // row within 8-row granule
  const int srcb = (((l & 7) ^ rgrp) << 4);      // swizzled byte offset in row
  #pragma unroll
  for (int gi = 0; gi < 4; ++gi) {
    int rb = (gi * 4 + w) * 8;                   // wave-granule base row
    gld16(g + (size_t)(rb + rgrp) * ldb + srcb, lds + (gi * 4 + w) * 1024);
  }
}

// 32B fp8 fragment (K=128): two 16B granules, swizzle-aware.  kb 32B-aligned.
static __device__ __forceinline__ i32x8 fragld32(const unsigned char* lds, int row, int kb) {
  const unsigned char* base = lds + row * 128;
  const int swz = (row & 7) << 4;
  const i32x4 lo = *(const i32x4*)(base + (kb ^ swz));
  const i32x4 hi = *(const i32x4*)(base + ((kb + 16) ^ swz));
  i32x8 r;
  r[0] = lo[0]; r[1] = lo[1]; r[2] = lo[2]; r[3] = lo[3];
  r[4] = hi[0]; r[5] = hi[1]; r[6] = hi[2]; r[7] = hi[3];
  return r;
}
// 16B fp4 fragment (K=128 at 4 bit): one granule, data in regs 0-3.
static __device__ __forceinline__ i32x8 fragld16(const unsigned char* lds, int row, int kb) {
  const i32x4 lo = *(const i32x4*)(lds + row * 128 + (kb ^ ((row & 7) << 4)));
  i32x8 r;
  r[0] = lo[0]; r[1] = lo[1]; r[2] = lo[2]; r[3] = lo[3];
  r[4] = 0; r[5] = 0; r[6] = 0; r[7] = 0;
  return r;
}

// fp4 x fp4 MX K-loop (kA): BK=256, TWO 16KB tiles staged, 2 substeps of
// 16 mfma_scale K=128.  cbsz=blgp=4 (fp4), scale 0x7F = 1.0 exact.
static __device__ __forceinline__ void gemm_fp4(unsigned char* sA, unsigned char* sB,
    const unsigned char* Ab, size_t lda, const unsigned char* Bb, size_t ldb,
    int nko, int w, int l, int wr, int wc, f4 acc[4][4]) {
  for (int kk = 0; kk < nko; ++kk) {
    stage_tile(Ab + (size_t)kk * 128, lda, sA, w, l);
    stage_tile(Bb + (size_t)kk * 128, ldb, sB, w, l);
    __syncthreads();
    #pragma unroll
    for (int ks = 0; ks < 2; ++ks) {
      const int kb = ks * 64 + (l >> 4) * 16;
      i32x8 af[4], bf[4];
      #pragma unroll
      for (int i = 0; i < 4; ++i)
        af[i] = fragld16(sA, wr * 64 + i * 16 + (l & 15), kb);
      #pragma unroll
      for (int j = 0; j < 4; ++j)
        bf[j] = fragld16(sB, wc * 64 + j * 16 + (l & 15), kb);
      #pragma unroll
      for (int i = 0; i < 4; ++i)
        #pragma unroll
        for (int j = 0; j < 4; ++j)
          acc[i][j] = __builtin_amdgcn_mfma_scale_f32_16x16x128_f8f6f4(
              af[i], bf[j], acc[i][j], 4, 4, 0, 0x7F7F7F7F, 0, 0x7F7F7F7F);
    }
    __syncthreads();
  }
}

// Mixed-format MX K-loop (kB): A fp8 (cbsz=0), B fp4 (blgp=4), BK=256.
static __device__ __forceinline__ void gemm_mixed(unsigned char* sA0, unsigned char* sA1,
    unsigned char* sB, const unsigned char* Ab, size_t lda,
    const unsigned char* Bb, size_t ldb, int nko, int w, int l, int wr, int wc,
    f4 acc[4][4]) {
  for (int kk = 0; kk < nko; ++kk) {
    stage_tile(Ab + (size_t)kk * 256, lda, sA0, w, l);
    stage_tile(Ab + (size_t)kk * 256 + 128, lda, sA1, w, l);
    stage_tile(Bb + (size_t)kk * 128, ldb, sB, w, l);
    __syncthreads();
    #pragma unroll
    for (int ks = 0; ks < 2; ++ks) {
      const unsigned char* sA = ks ? sA1 : sA0;
      const int kbA = (l >> 4) * 32;
      const int kbB = ks * 64 + (l >> 4) * 16;
      i32x8 af[4], bf[4];
      #pragma unroll
      for (int i = 0; i < 4; ++i)
        af[i] = fragld32(sA, wr * 64 + i * 16 + (l & 15), kbA);
      #pragma unroll
      for (int j = 0; j < 4; ++j)
        bf[j] = fragld16(sB, wc * 64 + j * 16 + (l & 15), kbB);
      #pragma unroll
      for (int i = 0; i < 4; ++i)
        #pragma unroll
        for (int j = 0; j < 4; ++j)
          acc[i][j] = __builtin_amdgcn_mfma_scale_f32_16x16x128_f8f6f4(
              af[i], bf[j], acc[i][j], 0, 4, 0, 0x7F7F7F7F, 0, 0x7F7F7F7F);
    }
    __syncthreads();
  }
}

// ---------------- prep kernels ----------------

static __device__ __forceinline__ float block_reduce_sum(float v, volatile float* sb, int t) {
  #pragma unroll
  for (int o = 32; o; o >>= 1) v += __shfl_xor(v, o);
  if ((t & 63) == 0) sb[t >> 6] = v;
  __syncthreads();
  float r = sb[0] + sb[1] + sb[2] + sb[3];
  __syncthreads();
  return r;
}

// embed -> RAW fp4 wn4 (adjacent-d nibble pairs, matching xr4) + winv[n]
__global__ __launch_bounds__(256) void prep_wn(const float* __restrict__ e,
                                               unsigned char* __restrict__ wn4,
                                               float* __restrict__ winv) {
  __shared__ float sb[4];
  const int n = blockIdx.x, t = threadIdx.x;
  const float4 v = *(const float4*)(e + (size_t)n * DIM + t * 4);
  float ss = v.x * v.x + v.y * v.y + v.z * v.z + v.w * v.w;
  ss = block_reduce_sum(ss, sb, t);
  if (t == 0) winv[n] = rsqrtf(fmaxf(ss, 1e-24f));
  *(unsigned short*)(wn4 + ((size_t)n * DIM + t * 4) / 2) = pk4_fp4(v.x, v.y, v.z, v.w);
}

// prep_x1: PURE STREAMING pass over x (one block per (m,b) row, no transpose):
// emits xr4 [b][m][d/2], optional xbf [m][b][d], and xinv[b][m] directly.
template <int XBF>
__global__ __launch_bounds__(256) void prep_x1(const float* __restrict__ x,
    unsigned char* __restrict__ xr4, unsigned short* __restrict__ xbf,
    float* __restrict__ xinv) {
  __shared__ float sb[4];
  const int r = blockIdx.x, t = threadIdx.x;   // r = m*8 + b
  const size_t roff = (size_t)r * DIM + t * 4;
  const float4 v = *(const float4*)(x + roff);
  float ss = v.x * v.x + v.y * v.y + v.z * v.z + v.w * v.w;
  ss = block_reduce_sum(ss, sb, t);
  const int m = r >> 3, b = r & 7;
  if (t == 0) xinv[b * N_TOK + m] = rsqrtf(fmaxf(ss, 1e-24f));
  if (XBF) {
    u16x4 bf;
    bf[0] = f2bf(v.x); bf[1] = f2bf(v.y); bf[2] = f2bf(v.z); bf[3] = f2bf(v.w);
    *(u16x4*)(xbf + roff) = bf;
  }
  *(unsigned short*)(xr4 + (((size_t)b * N_TOK + m) * DIM + t * 4) / 2) =
      pk4_fp4(v.x, v.y, v.z, v.w);
}

// prep_x2: tiny cached transpose xr4 -> XT4 (reads 8.4 MB L3-hot, writes 8.4).
// Block = 64 m x 64 d.  Phase 1: load packed bytes to LDS; phase 2: R16's
// proven nibble transpose, uint2 (8 B) contiguous stores per dl.
__global__ __launch_bounds__(256) void prep_x2(const unsigned char* __restrict__ xr4,
                                               unsigned char* __restrict__ XT4) {
  __shared__ unsigned char tile[64][36];   // packed fp4 pairs along d
  const int t = threadIdx.x;
  const int m0 = blockIdx.x * 64, d0 = blockIdx.y * 64, b = blockIdx.z;
  {
    const int ml = t >> 2, lane = t & 3;
    const uint2 v = *(const uint2*)(xr4 +
        (((size_t)b * N_TOK + m0 + ml) * DIM + d0) / 2 + lane * 8);
    *(unsigned int*)&tile[ml][lane * 8] = v.x;
    *(unsigned int*)&tile[ml][lane * 8 + 4] = v.y;
  }
  __syncthreads();
  {
    const int dl = t >> 2, mc = (t & 3) * 16;
    const int sh = (dl & 1) * 4, dby = dl >> 1;
    union { unsigned int u[2]; uint2 v; } o;
    o.u[0] = o.u[1] = 0;
    #pragma unroll
    for (int jj = 0; jj < 8; ++jj) {
      const unsigned int b0 = ((unsigned int)tile[mc + 2 * jj][dby] >> sh) & 15u;
      const unsigned int b1 = ((unsigned int)tile[mc + 2 * jj + 1][dby] >> sh) & 15u;
      o.u[jj >> 2] |= (b0 | (b1 << 4)) << ((jj & 3) * 8);
    }
    *(uint2*)(XT4 + (((size_t)b * DIM + d0 + dl) * (size_t)N_TOK + m0 + mc) / 2) = o.v;
  }
}

// ---------------- GEMM A: Sraw = wn4(fp4) . xr4(fp4)^T ; P = exp(S*winv*xinv) ----------------

__global__ __launch_bounds__(256, 4) void kA(
    const unsigned char* __restrict__ wn4, const unsigned char* __restrict__ xr4,
    const float* __restrict__ winv, const float* __restrict__ xinv,
    unsigned char* __restrict__ Pp, float* __restrict__ pden, int Mc, int c0) {
  __shared__ __align__(16) unsigned char sA[16384];
  __shared__ __align__(16) unsigned char sB[16384];
  __shared__ float pd[128][2];
  __shared__ float winv_s[128], xinv_s[128];

  const int t = threadIdx.x, l = t & 63, w = t >> 6;
  const int wr = w >> 1, wc = w & 1;

  // T1: chunked XCD swizzle (grid (16, Mc/128, 8); nwg % 8 == 0 -> bijective).
  const int gy = Mc >> 7;
  const int nwg = 16 * gy * 8;
  const int lin = blockIdx.x + 16 * (blockIdx.y + gy * blockIdx.z);
  const int wg = (lin & 7) * (nwg >> 3) + (lin >> 3);
  const int xx = wg & 15, yy = (wg >> 4) % gy, zz = (wg >> 4) / gy;

  const int q0 = xx * 128;
  const int m0l = yy * 128;
  const int b = zz;
  const int m0g = c0 + m0l;

  if (t < 128) winv_s[t] = winv[q0 + t];
  else         xinv_s[t - 128] = xinv[b * N_TOK + m0g + (t - 128)];

  f4 acc[4][4];
  #pragma unroll
  for (int i = 0; i < 4; ++i)
    #pragma unroll
    for (int j = 0; j < 4; ++j) acc[i][j] = (f4)0.0f;

  gemm_fp4(sA, sB,
           wn4 + (size_t)q0 * (DIM / 2), DIM / 2,
           xr4 + ((size_t)b * N_TOK + m0g) * (DIM / 2), DIM / 2,
           DIM / 256, w, l, wr, wc, acc);

  // epilogue: S = Sraw*winv*xinv in [-1,1]; P = exp(S) fp8 + row sums
  float ra[4][4];
  #pragma unroll
  for (int i = 0; i < 4; ++i)
    #pragma unroll
    for (int e = 0; e < 4; ++e) ra[i][e] = 0.0f;

  #pragma unroll
  for (int j = 0; j < 4; ++j) {
    const int cl = wc * 64 + j * 16 + (l & 15);  // local m col
    const float xv = xinv_s[cl];
    #pragma unroll
    for (int i = 0; i < 4; ++i)
      #pragma unroll
      for (int e = 0; e < 4; ++e) {
        const int row = wr * 64 + i * 16 + (l >> 4) * 4 + e;  // local q
        const float p = __expf(acc[i][j][e] * winv_s[row] * xv);
        ra[i][e] += p;
        Pp[((size_t)b * N_TOK + q0 + row) * (size_t)Mc + m0l + cl] = fp8_1(p);
      }
  }
  #pragma unroll
  for (int i = 0; i < 4; ++i)
    #pragma unroll
    for (int e = 0; e < 4; ++e) {
      float s = ra[i][e];
      s += __shfl_xor(s, 1); s += __shfl_xor(s, 2);
      s += __shfl_xor(s, 4); s += __shfl_xor(s, 8);
      if ((l & 15) == 0) pd[wr * 64 + i * 16 + (l >> 4) * 4 + e][wc] = s;
    }
  __syncthreads();
  if (t < 128)
    pden[((size_t)b * N_TOK + q0 + t) * 16 + (c0 >> 7) + yy] = pd[t][0] + pd[t][1];
}

// ---------------- GEMM B: O += P(fp8) . XT4(fp4)^T ; FINAL applies 1/den (bf16 if OBF) ----------------

template <int ACC, int FINAL, int OBF>
__global__ __launch_bounds__(256, 3) void kB(const unsigned char* __restrict__ Pp,
    const unsigned char* __restrict__ XT4, const float* __restrict__ pden,
    float* __restrict__ of32, unsigned short* __restrict__ obf, int Mc, int c0) {
  __shared__ __align__(16) unsigned char sA0[16384];
  __shared__ __align__(16) unsigned char sA1[16384];
  __shared__ __align__(16) unsigned char sB[16384];
  __shared__ float rden_s[128];

  const int t = threadIdx.x, l = t & 63, w = t >> 6;
  const int wr = w >> 1, wc = w & 1;

  // T1: chunked XCD swizzle, d0-INNER within XCD (P q-panel co-resident in L2).
  const int lin = blockIdx.x + 16 * (blockIdx.y + 8 * blockIdx.z);
  const int wg = (lin & 7) * 128 + (lin >> 3);
  const int s = wg & 127;
  const int d0 = (s & 7) * 128;
  const int q0 = (s >> 3) * 128;
  const int b = wg >> 7;

  f4 acc[4][4];
  #pragma unroll
  for (int i = 0; i < 4; ++i)
    #pragma unroll
    for (int j = 0; j < 4; ++j) acc[i][j] = (f4)0.0f;

  gemm_mixed(sA0, sA1, sB,
             Pp + ((size_t)b * N_TOK + q0) * (size_t)Mc, (size_t)Mc,
             XT4 + (((size_t)b * DIM + d0) * (size_t)N_TOK + c0) / 2, N_TOK / 2,
             Mc / 256, w, l, wr, wc, acc);

  if (FINAL) {
    if (t < 128) {
      const float* pp = pden + ((size_t)b * N_TOK + q0 + t) * 16;
      float ss = 0.0f;
      #pragma unroll
      for (int i = 0; i < 16; ++i) ss += pp[i];
      rden_s[t] = 1.0f / ss;
    }
    __syncthreads();
  }

  #pragma unroll
  for (int j = 0; j < 4; ++j) {
    const int cc = d0 + wc * 64 + j * 16 + (l & 15);
    #pragma unroll
    for (int i = 0; i < 4; ++i)
      #pragma unroll
      for (int e = 0; e < 4; ++e) {
        const int rl = wr * 64 + i * 16 + (l >> 4) * 4 + e;
        const size_t oi = (size_t)(q0 + rl) * (BATCH * DIM) + (size_t)b * DIM + cc;
        float v = acc[i][j][e];
        if (ACC) v += of32[oi];
        if (FINAL) {
          v *= rden_s[rl];
          if (OBF) { obf[oi] = f2bf(v); continue; }
        }
        of32[oi] = v;
      }
  }
}

// ---------------- final: out = LN(O + x) * gamma + beta ----------------

template <int OBF, int XBF>
__global__ __launch_bounds__(256) void kLN(const float* __restrict__ gamma,
    const float* __restrict__ beta, const unsigned short* __restrict__ obf,
    const float* __restrict__ of32, const unsigned short* __restrict__ xbf,
    const float* __restrict__ x, float* __restrict__ out) {
  __shared__ float sb[8];
  const int r = blockIdx.x;            // r = n*8 + b
  const int t = threadIdx.x;

  const size_t base = (size_t)r * DIM + t * 4;
  float o0, o1, o2, o3, x0, x1, x2, x3;
  if (OBF) {
    const ushort4 u = *(const ushort4*)(obf + base);
    o0 = bf2f(u.x); o1 = bf2f(u.y); o2 = bf2f(u.z); o3 = bf2f(u.w);
  } else {
    const float4 o4 = *(const float4*)(of32 + base);
    o0 = o4.x; o1 = o4.y; o2 = o4.z; o3 = o4.w;
  }
  if (XBF) {
    const ushort4 u = *(const ushort4*)(xbf + base);
    x0 = bf2f(u.x); x1 = bf2f(u.y); x2 = bf2f(u.z); x3 = bf2f(u.w);
  } else {
    const float4 x4 = *(const float4*)(x + base);
    x0 = x4.x; x1 = x4.y; x2 = x4.z; x3 = x4.w;
  }
  const float y0 = o0 + x0, y1 = o1 + x1, y2 = o2 + x2, y3 = o3 + x3;

  float s1 = y0 + y1 + y2 + y3;
  float s2 = y0 * y0 + y1 * y1 + y2 * y2 + y3 * y3;
  #pragma unroll
  for (int o = 32; o; o >>= 1) { s1 += __shfl_xor(s1, o); s2 += __shfl_xor(s2, o); }
  if ((t & 63) == 0) { sb[t >> 6] = s1; sb[4 + (t >> 6)] = s2; }
  __syncthreads();
  s1 = sb[0] + sb[1] + sb[2] + sb[3];
  s2 = sb[4] + sb[5] + sb[6] + sb[7];

  const float mean = s1 * (1.0f / DIM);
  const float var = s2 * (1.0f / DIM) - mean * mean;
  const float rstd = rsqrtf(var + 1e-5f);

  const float4 g4 = *(const float4*)(gamma + t * 4);
  const float4 b4 = *(const float4*)(beta + t * 4);
  float4 rr;
  rr.x = (y0 - mean) * rstd * g4.x + b4.x;
  rr.y = (y1 - mean) * rstd * g4.y + b4.y;
  rr.z = (y2 - mean) * rstd * g4.z + b4.z;
  rr.w = (y3 - mean) * rstd * g4.w + b4.w;
  *(float4*)(out + (size_t)r * DIM + t * 4) = rr;
}

// ---------------- launch ----------------

extern "C" void kernel_launch(void* const* d_in, const int* in_sizes, int n_in,
                              void* d_out, int out_size, void* d_ws, size_t ws_size,
                              hipStream_t stream) {
  (void)in_sizes; (void)n_in; (void)out_size;
  const float* x     = (const float*)d_in[0];
  const float* embed = (const float*)d_in[1];
  const float* gamma = (const float*)d_in[2];
  const float* beta  = (const float*)d_in[3];
  float* out = (float*)d_out;

  size_t off = 0;
  char* ws = (char*)d_ws;
  auto take = [&](size_t bytes) { char* p = ws + off; off += bytes; return p; };
  unsigned char* XT4  = (unsigned char*)take((size_t)BATCH * DIM * N_TOK / 2);  //  8.4 MB
  unsigned char* xr4  = (unsigned char*)take((size_t)BATCH * N_TOK * DIM / 2);  //  8.4 MB
  unsigned char* wn4  = (unsigned char*)take((size_t)N_TOK * DIM / 2);          //  1.0 MB
  float* winv   = (float*)take((size_t)N_TOK * 4);                              //  8 KB
  float* xinv   = (float*)take((size_t)BATCH * N_TOK * 4);                      // 64 KB
  float* pden   = (float*)take((size_t)BATCH * N_TOK * 16 * 4);                 //  2.1 MB
  const size_t fixed = off;

  int Mc = 2048;
  while (Mc > 256 && fixed + (size_t)BATCH * N_TOK * Mc > ws_size) Mc >>= 1;
  unsigned char* Pp = (unsigned char*)take((size_t)BATCH * N_TOK * Mc);         // 33.6 MB full

  const size_t half = (size_t)N_TOK * BATCH * DIM * 2;                          // 33.6 MB
  const int use_obf = (off + half <= ws_size) ? 1 : 0;
  unsigned short* obf = use_obf ? (unsigned short*)take(half) : (unsigned short*)out;
  const int use_xbf = (off + half <= ws_size) ? 1 : 0;
  unsigned short* xbf = use_xbf ? (unsigned short*)take(half) : (unsigned short*)out;

  prep_wn<<<N_TOK, 256, 0, stream>>>(embed, wn4, winv);
  if (use_xbf)
    prep_x1<1><<<N_TOK * BATCH, 256, 0, stream>>>(x, xr4, xbf, xinv);
  else
    prep_x1<0><<<N_TOK * BATCH, 256, 0, stream>>>(x, xr4, xbf, xinv);
  prep_x2<<<dim3(N_TOK / 64, DIM / 64, BATCH), 256, 0, stream>>>(xr4, XT4);

  const int nchunk = N_TOK / Mc;
  for (int ci = 0; ci < nchunk; ++ci) {
    const int c0 = ci * Mc;
    kA<<<dim3(16, Mc / 128, BATCH), 256, 0, stream>>>(wn4, xr4, winv, xinv, Pp, pden, Mc, c0);
    const bool first = (ci == 0), last = (ci == nchunk - 1);
    const dim3 gB(16, 8, BATCH);
    if (last) {
      if (use_obf) {
        if (first) kB<0, 1, 1><<<gB, 256, 0, stream>>>(Pp, XT4, pden, out, obf, Mc, c0);
        else       kB<1, 1, 1><<<gB, 256, 0, stream>>>(Pp, XT4, pden, out, obf, Mc, c0);
      } else {
        if (first) kB<0, 1, 0><<<gB, 256, 0, stream>>>(Pp, XT4, pden, out, obf, Mc, c0);
        else       kB<1, 1, 0><<<gB, 256, 0, stream>>>(Pp, XT4, pden, out, obf, Mc, c0);
      }
    } else {
      if (first) kB<0, 0, 0><<<gB, 256, 0, stream>>>(Pp, XT4, pden, out, obf, Mc, c0);
      else       kB<1, 0, 0><<<gB, 256, 0, stream>>>(Pp, XT4, pden, out, obf, Mc, c0);
    }
  }
  if (use_obf) {
    if (use_xbf) kLN<1, 1><<<N_TOK * BATCH, 256, 0, stream>>>(gamma, beta, obf, out, xbf, x, out);
    else         kLN<1, 0><<<N_TOK * BATCH, 256, 0, stream>>>(gamma, beta, obf, out, xbf, x, out);
  } else {
    if (use_xbf) kLN<0, 1><<<N_TOK * BATCH, 256, 0, stream>>>(gamma, beta, obf, out, xbf, x, out);
    else         kLN<0, 0><<<N_TOK * BATCH, 256, 0, stream>>>(gamma, beta, obf, out, xbf, x, out);
  }
}